// Round 1
// baseline (1880.680 us; speedup 1.0000x reference)
//
#include <hip/hip_runtime.h>
#include <math.h>

#define TPB 256
#define BM 64
#define BN 64
#define BKK 16

// ---------------- GEMM: C(L,S) = A(L,D) * B(S,D)^T  (fp32) ----------------
__global__ __launch_bounds__(TPB) void gemm_nt(const float* __restrict__ A,
                                               const float* __restrict__ B,
                                               float* __restrict__ C,
                                               int L, int S, int D) {
  __shared__ float As[BKK][BM + 4];
  __shared__ float Bs[BKK][BN + 4];
  const int tid = threadIdx.x;
  const int tx = tid & 15;   // n group (4 cols each)
  const int ty = tid >> 4;   // m group (4 rows each)
  const int bm = blockIdx.y * BM;
  const int bn = blockIdx.x * BN;
  const int lk = tid & 15;   // k index for loads
  const int lm = tid >> 4;   // row group for loads
  float acc[4][4] = {};
  for (int k0 = 0; k0 < D; k0 += BKK) {
#pragma unroll
    for (int r = 0; r < 4; ++r) {
      int row = lm + r * 16;
      int gk = k0 + lk;
      int gm = bm + row;
      As[lk][row] = (gm < L && gk < D) ? A[(size_t)gm * D + gk] : 0.0f;
      int gn = bn + row;
      Bs[lk][row] = (gn < S && gk < D) ? B[(size_t)gn * D + gk] : 0.0f;
    }
    __syncthreads();
#pragma unroll
    for (int k = 0; k < BKK; ++k) {
      float a0 = As[k][ty * 4 + 0];
      float a1 = As[k][ty * 4 + 1];
      float a2 = As[k][ty * 4 + 2];
      float a3 = As[k][ty * 4 + 3];
      float b0 = Bs[k][tx * 4 + 0];
      float b1 = Bs[k][tx * 4 + 1];
      float b2 = Bs[k][tx * 4 + 2];
      float b3 = Bs[k][tx * 4 + 3];
      acc[0][0] += a0 * b0; acc[0][1] += a0 * b1; acc[0][2] += a0 * b2; acc[0][3] += a0 * b3;
      acc[1][0] += a1 * b0; acc[1][1] += a1 * b1; acc[1][2] += a1 * b2; acc[1][3] += a1 * b3;
      acc[2][0] += a2 * b0; acc[2][1] += a2 * b1; acc[2][2] += a2 * b2; acc[2][3] += a2 * b3;
      acc[3][0] += a3 * b0; acc[3][1] += a3 * b1; acc[3][2] += a3 * b2; acc[3][3] += a3 * b3;
    }
    __syncthreads();
  }
#pragma unroll
  for (int i = 0; i < 4; ++i) {
    int m = bm + ty * 4 + i;
    if (m >= L) continue;
#pragma unroll
    for (int j = 0; j < 4; ++j) {
      int n = bn + tx * 4 + j;
      if (n < S) C[(size_t)m * S + n] = acc[i][j];
    }
  }
}

// ---------------- per-row max & sumexp ----------------
__global__ __launch_bounds__(TPB) void row_stats(const float* __restrict__ sim, int S,
                                                 float* __restrict__ rm, float* __restrict__ rs) {
  __shared__ float red[TPB];
  const int l = blockIdx.x;
  const float* row = sim + (size_t)l * S;
  float m = -INFINITY;
  for (int j = threadIdx.x; j < S; j += TPB) m = fmaxf(m, row[j]);
  red[threadIdx.x] = m;
  __syncthreads();
  for (int st = TPB / 2; st > 0; st >>= 1) {
    if (threadIdx.x < st) red[threadIdx.x] = fmaxf(red[threadIdx.x], red[threadIdx.x + st]);
    __syncthreads();
  }
  m = red[0];
  __syncthreads();
  float s = 0.f;
  for (int j = threadIdx.x; j < S; j += TPB) s += expf(row[j] - m);
  red[threadIdx.x] = s;
  __syncthreads();
  for (int st = TPB / 2; st > 0; st >>= 1) {
    if (threadIdx.x < st) red[threadIdx.x] += red[threadIdx.x + st];
    __syncthreads();
  }
  if (threadIdx.x == 0) { rm[l] = m; rs[l] = red[0]; }
}

// ---------------- per-column stats: chunked online, then combine ----------------
__global__ __launch_bounds__(TPB) void col_stats_part(const float* __restrict__ sim, int L, int S,
                                                      float* __restrict__ pm, float* __restrict__ ps) {
  int s = blockIdx.x * TPB + threadIdx.x;
  if (s >= S) return;
  int l0 = blockIdx.y * 256;
  int l1 = l0 + 256; if (l1 > L) l1 = L;
  float m = -INFINITY, acc = 0.f;
  for (int l = l0; l < l1; ++l) {
    float v = sim[(size_t)l * S + s];
    if (v > m) { acc = acc * expf(m - v) + 1.f; m = v; }
    else acc += expf(v - m);
  }
  pm[(size_t)blockIdx.y * S + s] = m;
  ps[(size_t)blockIdx.y * S + s] = acc;
}

__global__ __launch_bounds__(TPB) void col_combine(const float* __restrict__ pm, const float* __restrict__ ps,
                                                   int S, int nch,
                                                   float* __restrict__ cm, float* __restrict__ cs) {
  int s = blockIdx.x * TPB + threadIdx.x;
  if (s >= S) return;
  float m = -INFINITY, acc = 0.f;
  for (int c = 0; c < nch; ++c) {
    float m2 = pm[(size_t)c * S + s];
    float s2 = ps[(size_t)c * S + s];
    if (m2 > m) { acc = acc * expf(m - m2) + s2; m = m2; }
    else acc += s2 * expf(m2 - m);
  }
  cm[s] = m;
  cs[s] = acc;
}

// ---------------- finalize: conf = softmax_col * softmax_row ----------------
// MODE 0: argmax only. MODE 1: write conf in place + argmax. MODE 2: write conf/TEMP masked (>1), no argmax.
template <int MODE>
__global__ __launch_bounds__(TPB) void finalize_rows(float* __restrict__ sim, int S,
                                                     const float* __restrict__ rm, const float* __restrict__ rs,
                                                     const float* __restrict__ cm, const float* __restrict__ cs,
                                                     int* __restrict__ amax) {
  __shared__ float rv[TPB];
  __shared__ int ri[TPB];
  const int l = blockIdx.x;
  const float rmax = rm[l];
  const float rsum = rs[l];
  float* row = sim + (size_t)l * S;
  float bv = -INFINITY;
  int bi = 0;
  for (int j = threadIdx.x; j < S; j += TPB) {
    float v = row[j];
    float a = expf(v - rmax) / rsum;
    float b = expf(v - cm[j]) / cs[j];
    float conf = a * b;
    if (MODE == 1) row[j] = conf;
    if (MODE == 2) {
      float c = conf / 0.1f;
      row[j] = (c > 1.0f) ? c : 0.0f;
    }
    if (MODE != 2) {
      if (conf > bv) { bv = conf; bi = j; }
    }
  }
  if (MODE == 2) return;
  rv[threadIdx.x] = bv;
  ri[threadIdx.x] = bi;
  __syncthreads();
  for (int st = TPB / 2; st > 0; st >>= 1) {
    if (threadIdx.x < st) {
      float v2 = rv[threadIdx.x + st];
      int i2 = ri[threadIdx.x + st];
      if (v2 > rv[threadIdx.x] || (v2 == rv[threadIdx.x] && i2 < ri[threadIdx.x])) {
        rv[threadIdx.x] = v2;
        ri[threadIdx.x] = i2;
      }
    }
    __syncthreads();
  }
  if (threadIdx.x == 0) amax[l] = ri[0];
}

// ---------------- small builders ----------------
// X16 (768 x 400): c<256: t2[p,c]; c<512: f116_0[p,c-256]; else f116_1[idx[p], c-512]
__global__ void build_x16(const float* __restrict__ t2, const float* __restrict__ f0,
                          const float* __restrict__ f1, const int* __restrict__ idx,
                          float* __restrict__ X) {
  int id = blockIdx.x * TPB + threadIdx.x;
  if (id >= 768 * 400) return;
  int c = id / 400, p = id % 400;
  float v;
  if (c < 256) v = t2[p * 256 + c];
  else if (c < 512) v = f0[p * 256 + (c - 256)];
  else v = f1[idx[p] * 256 + (c - 512)];
  X[id] = v;
}

// X8 (512 x 1600): c<256: f18_0[p,c]; else f18_1[idx[p], c-256]
__global__ void build_x8(const float* __restrict__ f0, const float* __restrict__ f1,
                         const int* __restrict__ idx, float* __restrict__ X) {
  int id = blockIdx.x * TPB + threadIdx.x;
  if (id >= 512 * 1600) return;
  int c = id / 1600, p = id % 1600;
  float v = (c < 256) ? f0[p * 256 + c] : f1[idx[p] * 256 + (c - 256)];
  X[id] = v;
}

// generic conv1x1: Y(O x P) = W(O x C) * X(C x P)
__global__ void conv1x1(const float* __restrict__ W, const float* __restrict__ X,
                        float* __restrict__ Y, int O, int C, int P) {
  int id = blockIdx.x * TPB + threadIdx.x;
  if (id >= O * P) return;
  int o = id / P, p = id % P;
  float acc = 0.f;
  for (int c = 0; c < C; ++c) acc += W[o * C + c] * X[(size_t)c * P + p];
  Y[id] = acc;
}

// generic average pool: in C x H x H -> out C x (H/f) x (H/f)
__global__ void pool_k(const float* __restrict__ in, float* __restrict__ out, int C, int H, int f) {
  int h = H / f;
  int id = blockIdx.x * TPB + threadIdx.x;
  if (id >= C * h * h) return;
  int c = id / (h * h);
  int r = id % (h * h);
  int py = r / h, px = r % h;
  float s = 0.f;
  for (int i = 0; i < f; ++i)
    for (int j = 0; j < f; ++j)
      s += in[(size_t)c * H * H + (size_t)(py * f + i) * H + (px * f + j)];
  out[id] = s / (float)(f * f);
}

// feats14 gather + pool (80x80 -> 10x10, 392 ch): c<196 f14_0[p,c] else f14_1[idx[p],c-196]
__global__ void pool14(const float* __restrict__ f0, const float* __restrict__ f1,
                       const int* __restrict__ idx, float* __restrict__ out) {
  int id = blockIdx.x * TPB + threadIdx.x;
  if (id >= 392 * 100) return;
  int c = id / 100;
  int r = id % 100;
  int py = r / 10, px = r % 10;
  float s = 0.f;
  for (int i = 0; i < 8; ++i)
    for (int j = 0; j < 8; ++j) {
      int p = (py * 8 + i) * 80 + (px * 8 + j);
      float v = (c < 196) ? f0[p * 196 + c] : f1[idx[p] * 196 + (c - 196)];
      s += v;
    }
  out[id] = s * (1.0f / 64.0f);
}

// Xt3 (1100 x 100): [t3_img(196), t2p(256), f18p(256), f14p(392)]
__global__ void build_xt3(const float* __restrict__ t3, const float* __restrict__ t2p,
                          const float* __restrict__ f18p, const float* __restrict__ f14p,
                          float* __restrict__ X) {
  int id = blockIdx.x * TPB + threadIdx.x;
  if (id >= 1100 * 100) return;
  int c = id / 100, p = id % 100;
  float v;
  if (c < 196) v = t3[p * 196 + c];
  else if (c < 452) v = t2p[(c - 196) * 100 + p];
  else if (c < 708) v = f18p[(c - 452) * 100 + p];
  else v = f14p[(c - 708) * 100 + p];
  X[id] = v;
}

// Xt4 (256 x 25): c<128: t3d[c,p]; else t4[p, c-128]
__global__ void build_xt4(const float* __restrict__ t3d, const float* __restrict__ t4,
                          float* __restrict__ X) {
  int id = blockIdx.x * TPB + threadIdx.x;
  if (id >= 256 * 25) return;
  int c = id / 25, p = id % 25;
  X[id] = (c < 128) ? t3d[c * 25 + p] : t4[p * 128 + (c - 128)];
}

// topic: dmatrix12 = feats12(12800x128) . t4seq(25x128)^T, argmax over 25
__global__ __launch_bounds__(TPB) void topic_k(const float* __restrict__ f0, const float* __restrict__ f1,
                                               const float* __restrict__ t4d, float* __restrict__ out) {
  __shared__ float s_t4[25 * 128];
  for (int i = threadIdx.x; i < 25 * 128; i += TPB) {
    int k = i >> 7, d = i & 127;
    s_t4[i] = t4d[d * 25 + k];   // t4seq[k][d] = t4d[d][k]
  }
  __syncthreads();
  int m = blockIdx.x * TPB + threadIdx.x;
  if (m >= 12800) return;
  const float* row = (m < 6400) ? (f0 + (size_t)m * 128) : (f1 + (size_t)(m - 6400) * 128);
  float acc[25];
#pragma unroll
  for (int k = 0; k < 25; ++k) acc[k] = 0.f;
  for (int d = 0; d < 128; ++d) {
    float x = row[d];
#pragma unroll
    for (int k = 0; k < 25; ++k) acc[k] += x * s_t4[k * 128 + d];
  }
  int best = 0;
  float bv = acc[0];
#pragma unroll
  for (int k = 1; k < 25; ++k)
    if (acc[k] > bv) { bv = acc[k]; best = k; }
  out[m] = (float)best;
}

static inline int cdiv(int a, int b) { return (a + b - 1) / b; }

extern "C" void kernel_launch(void* const* d_in, const int* in_sizes, int n_in,
                              void* d_out, int out_size, void* d_ws, size_t ws_size,
                              hipStream_t stream) {
  const float* f12_0 = (const float*)d_in[0];
  const float* f12_1 = (const float*)d_in[1];
  const float* f14_0 = (const float*)d_in[2];
  const float* f14_1 = (const float*)d_in[3];
  const float* f18_0 = (const float*)d_in[4];
  const float* f18_1 = (const float*)d_in[5];
  const float* f116_0 = (const float*)d_in[6];
  const float* f116_1 = (const float*)d_in[7];
  /* t1 = d_in[8] unused */
  const float* t2 = (const float*)d_in[9];
  const float* t3 = (const float*)d_in[10];
  const float* t4 = (const float*)d_in[11];
  const float* W16 = (const float*)d_in[12];
  const float* W8 = (const float*)d_in[13];
  const float* Wt3 = (const float*)d_in[14];
  const float* Wt4 = (const float*)d_in[15];

  float* out = (float*)d_out;
  float* conf18 = out;                        // 1600*1600
  float* conf12 = out + 2560000;              // 6400*6400 (also scratch for sim14, then sim12)
  float* topic = out + 2560000 + 40960000;    // 12800

  // workspace carve-out
  float* w = (float*)d_ws;
  auto alloc = [&](size_t n) { float* p = w; w += ((n + 63) & ~(size_t)63); return p; };

  float* sim116 = alloc(400 * 400);
  float* rm116 = alloc(400); float* rs116 = alloc(400);
  float* cm116 = alloc(400); float* cs116 = alloc(400);
  int* idx116 = (int*)alloc(400);
  float* rm18 = alloc(1600); float* rs18 = alloc(1600);
  float* cm18 = alloc(1600); float* cs18 = alloc(1600);
  int* idx18 = (int*)alloc(1600);
  float* rm14 = alloc(6400); float* rs14 = alloc(6400);
  float* cm14 = alloc(6400); float* cs14 = alloc(6400);
  int* idx14 = (int*)alloc(6400);
  float* rm12 = alloc(6400); float* rs12 = alloc(6400);
  float* cm12 = alloc(6400); float* cs12 = alloc(6400);
  float* cpm = alloc(25 * 6400);  // col partial max (max chunks = 25)
  float* cps = alloc(25 * 6400);  // col partial sum
  float* X16 = alloc(768 * 400);
  float* t2_ = alloc(256 * 400);
  float* X8 = alloc(512 * 1600);
  float* conv18b = alloc(256 * 1600);
  float* f18p = alloc(256 * 100);
  float* t2p = alloc(256 * 100);
  float* f14p = alloc(392 * 100);
  float* Xt3 = alloc(1100 * 100);
  float* t3conv = alloc(128 * 100);
  float* t3d = alloc(128 * 25);
  float* Xt4 = alloc(256 * 25);
  float* t4d = alloc(128 * 25);

  // ---------------- conf116 -> idx116 ----------------
  {
    int L = 400, S = 400, D = 256;
    gemm_nt<<<dim3(cdiv(S, BN), cdiv(L, BM)), TPB, 0, stream>>>(f116_0, f116_1, sim116, L, S, D);
    row_stats<<<L, TPB, 0, stream>>>(sim116, S, rm116, rs116);
    int nch = cdiv(L, 256);
    col_stats_part<<<dim3(cdiv(S, TPB), nch), TPB, 0, stream>>>(sim116, L, S, cpm, cps);
    col_combine<<<cdiv(S, TPB), TPB, 0, stream>>>(cpm, cps, S, nch, cm116, cs116);
    finalize_rows<0><<<L, TPB, 0, stream>>>(sim116, S, rm116, rs116, cm116, cs116, idx116);
  }

  // ---------------- t2_ = conv1x1(W16, [t2_img; feats116]) ----------------
  build_x16<<<cdiv(768 * 400, TPB), TPB, 0, stream>>>(t2, f116_0, f116_1, idx116, X16);
  conv1x1<<<cdiv(256 * 400, TPB), TPB, 0, stream>>>(W16, X16, t2_, 256, 768, 400);

  // ---------------- conf18 (output) + idx18 ----------------
  {
    int L = 1600, S = 1600, D = 256;
    gemm_nt<<<dim3(cdiv(S, BN), cdiv(L, BM)), TPB, 0, stream>>>(f18_0, f18_1, conf18, L, S, D);
    row_stats<<<L, TPB, 0, stream>>>(conf18, S, rm18, rs18);
    int nch = cdiv(L, 256);
    col_stats_part<<<dim3(cdiv(S, TPB), nch), TPB, 0, stream>>>(conf18, L, S, cpm, cps);
    col_combine<<<cdiv(S, TPB), TPB, 0, stream>>>(cpm, cps, S, nch, cm18, cs18);
    finalize_rows<1><<<L, TPB, 0, stream>>>(conf18, S, rm18, rs18, cm18, cs18, idx18);
  }

  // ---------------- feats18 path ----------------
  build_x8<<<cdiv(512 * 1600, TPB), TPB, 0, stream>>>(f18_0, f18_1, idx18, X8);
  conv1x1<<<cdiv(256 * 1600, TPB), TPB, 0, stream>>>(W8, X8, conv18b, 256, 512, 1600);
  pool_k<<<cdiv(256 * 100, TPB), TPB, 0, stream>>>(conv18b, f18p, 256, 40, 4);
  pool_k<<<cdiv(256 * 100, TPB), TPB, 0, stream>>>(t2_, t2p, 256, 20, 2);

  // ---------------- conf14 -> idx14 (sim14 staged in conf12 output region) ----------------
  {
    int L = 6400, S = 6400, D = 196;
    gemm_nt<<<dim3(cdiv(S, BN), cdiv(L, BM)), TPB, 0, stream>>>(f14_0, f14_1, conf12, L, S, D);
    row_stats<<<L, TPB, 0, stream>>>(conf12, S, rm14, rs14);
    int nch = cdiv(L, 256);
    col_stats_part<<<dim3(cdiv(S, TPB), nch), TPB, 0, stream>>>(conf12, L, S, cpm, cps);
    col_combine<<<cdiv(S, TPB), TPB, 0, stream>>>(cpm, cps, S, nch, cm14, cs14);
    finalize_rows<0><<<L, TPB, 0, stream>>>(conf12, S, rm14, rs14, cm14, cs14, idx14);
  }
  pool14<<<cdiv(392 * 100, TPB), TPB, 0, stream>>>(f14_0, f14_1, idx14, f14p);

  // ---------------- t3 path ----------------
  build_xt3<<<cdiv(1100 * 100, TPB), TPB, 0, stream>>>(t3, t2p, f18p, f14p, Xt3);
  conv1x1<<<cdiv(128 * 100, TPB), TPB, 0, stream>>>(Wt3, Xt3, t3conv, 128, 1100, 100);
  pool_k<<<cdiv(128 * 25, TPB), TPB, 0, stream>>>(t3conv, t3d, 128, 10, 2);

  // ---------------- t4 path ----------------
  build_xt4<<<cdiv(256 * 25, TPB), TPB, 0, stream>>>(t3d, t4, Xt4);
  conv1x1<<<cdiv(128 * 25, TPB), TPB, 0, stream>>>(Wt4, Xt4, t4d, 128, 256, 25);

  // ---------------- topic_idx ----------------
  topic_k<<<cdiv(12800, TPB), TPB, 0, stream>>>(f12_0, f12_1, t4d, topic);

  // ---------------- conf12 (output, in place over its own region) ----------------
  {
    int L = 6400, S = 6400, D = 128;
    gemm_nt<<<dim3(cdiv(S, BN), cdiv(L, BM)), TPB, 0, stream>>>(f12_0, f12_1, conf12, L, S, D);
    row_stats<<<L, TPB, 0, stream>>>(conf12, S, rm12, rs12);
    int nch = cdiv(L, 256);
    col_stats_part<<<dim3(cdiv(S, TPB), nch), TPB, 0, stream>>>(conf12, L, S, cpm, cps);
    col_combine<<<cdiv(S, TPB), TPB, 0, stream>>>(cpm, cps, S, nch, cm12, cs12);
    finalize_rows<2><<<L, TPB, 0, stream>>>(conf12, S, rm12, rs12, cm12, cs12, nullptr);
  }
}

// Round 3
// 1694.913 us; speedup vs baseline: 1.1096x; 1.1096x over previous
//
#include <hip/hip_runtime.h>
#include <math.h>

#define TPB 256

typedef __attribute__((ext_vector_type(4))) float f32x4;
typedef short s16x8 __attribute__((ext_vector_type(8)));

static inline int cdiv(int a, int b) { return (a + b - 1) / b; }

#define GLOAD_LDS16(g, l)                                                        \
  __builtin_amdgcn_global_load_lds(                                              \
      (const __attribute__((address_space(1))) unsigned int*)(const void*)(g),   \
      (__attribute__((address_space(3))) unsigned int*)(void*)(l), 16, 0, 0)

__device__ __forceinline__ unsigned short f2bf_rne(float f) {
  unsigned int u = __float_as_uint(f);
  return (unsigned short)((u + 0x7FFFu + ((u >> 16) & 1u)) >> 16);
}
__device__ __forceinline__ float bf2f(unsigned short h) {
  return __uint_as_float(((unsigned int)h) << 16);
}

// ---------------- 3-term split-bf16 pack: out[m][k], section s = k/D -------
// codes: 2 bits/section: 0 = hi = bf16(a); 1 = mid = bf16(a-hi); 2 = lo = bf16(a-hi-mid).
// Sections >= 6 (padding) write 0.
__global__ __launch_bounds__(TPB) void pack_split(const float* __restrict__ X,
                                                  unsigned short* __restrict__ out,
                                                  int M, int D, int K2p, int codes) {
  int id = blockIdx.x * TPB + threadIdx.x;
  if (id >= M * K2p) return;
  int m = id / K2p, k = id - m * K2p;
  int s = k / D;
  unsigned short v = 0;
  if (s < 6) {
    int d = k - s * D;
    float a = X[(size_t)m * D + d];
    unsigned short h = f2bf_rne(a);
    int code = (codes >> (2 * s)) & 3;
    if (code == 0) {
      v = h;
    } else {
      float r1 = a - bf2f(h);
      unsigned short mi = f2bf_rne(r1);
      if (code == 1) v = mi;
      else v = f2bf_rne(r1 - bf2f(mi));
    }
  }
  out[id] = v;
}

// ---------------- MFMA GEMM: C(M,N) = A(M,K) * B(N,K)^T, bf16 in fp32 out ----
// K multiple of 64. 128x128 tile, 4 waves (2x2 of 64x64), BK=64.
__global__ __launch_bounds__(TPB) void gemm_bf16_nt(const unsigned short* __restrict__ A,
                                                    const unsigned short* __restrict__ B,
                                                    float* __restrict__ C,
                                                    int M, int N, int K) {
  __shared__ __align__(16) unsigned short As[128 * 64];
  __shared__ __align__(16) unsigned short Bs[128 * 64];
  const int tid = threadIdx.x;
  const int lane = tid & 63;
  const int w = tid >> 6;
  const int wm = w >> 1, wn = w & 1;
  const int bm = blockIdx.y * 128, bn = blockIdx.x * 128;

  f32x4 acc[4][4];
#pragma unroll
  for (int m = 0; m < 4; ++m)
#pragma unroll
    for (int n = 0; n < 4; ++n) acc[m][n] = (f32x4){0.f, 0.f, 0.f, 0.f};

  // staging: instruction i covers LDS chunk slot q = (w*4+i)*64 + lane.
  // LDS slot q = r*8 + cp holds global chunk c = cp ^ (r&7) of row r (XOR swizzle).
  const unsigned short* gA[4];
  const unsigned short* gB[4];
#pragma unroll
  for (int i = 0; i < 4; ++i) {
    int q = (w * 4 + i) * 64 + lane;
    int r = q >> 3;
    int c = (q & 7) ^ (r & 7);
    int ga = bm + r; if (ga >= M) ga = M - 1;
    int gb = bn + r; if (gb >= N) gb = N - 1;
    gA[i] = A + (size_t)ga * K + c * 8;
    gB[i] = B + (size_t)gb * K + c * 8;
  }

  for (int k0 = 0; k0 < K; k0 += 64) {
#pragma unroll
    for (int i = 0; i < 4; ++i) {
      GLOAD_LDS16(gA[i] + k0, As + (w * 4 + i) * 512);
      GLOAD_LDS16(gB[i] + k0, Bs + (w * 4 + i) * 512);
    }
    __syncthreads();
#pragma unroll
    for (int ks = 0; ks < 2; ++ks) {
      s16x8 af[4], bfr[4];
      const int c0 = ks * 4 + (lane >> 4);
#pragma unroll
      for (int m = 0; m < 4; ++m) {
        int ra = wm * 64 + m * 16 + (lane & 15);
        af[m] = *(const s16x8*)(As + ra * 64 + ((c0 ^ (ra & 7)) * 8));
        int rb = wn * 64 + m * 16 + (lane & 15);
        bfr[m] = *(const s16x8*)(Bs + rb * 64 + ((c0 ^ (rb & 7)) * 8));
      }
#pragma unroll
      for (int m = 0; m < 4; ++m)
#pragma unroll
        for (int n = 0; n < 4; ++n)
          acc[m][n] = __builtin_amdgcn_mfma_f32_16x16x32_bf16(af[m], bfr[n], acc[m][n], 0, 0, 0);
    }
    __syncthreads();
  }

  // C/D layout: col = lane&15, row = (lane>>4)*4 + j   [verified m89]
#pragma unroll
  for (int m = 0; m < 4; ++m) {
    int row0 = bm + wm * 64 + m * 16 + (lane >> 4) * 4;
#pragma unroll
    for (int n = 0; n < 4; ++n) {
      int col = bn + wn * 64 + n * 16 + (lane & 15);
      if (col < N) {
#pragma unroll
        for (int j = 0; j < 4; ++j) {
          int r2 = row0 + j;
          if (r2 < M) C[(size_t)r2 * N + col] = acc[m][n][j];
        }
      }
    }
  }
}

// ---------------- per-column stats: chunked online, then combine ----------------
__global__ __launch_bounds__(TPB) void col_stats_part(const float* __restrict__ sim, int L, int S,
                                                      float* __restrict__ pm, float* __restrict__ ps) {
  int s = blockIdx.x * TPB + threadIdx.x;
  if (s >= S) return;
  int l0 = blockIdx.y * 256;
  int l1 = l0 + 256; if (l1 > L) l1 = L;
  float m = -INFINITY, acc = 0.f;
  for (int l = l0; l < l1; ++l) {
    float v = sim[(size_t)l * S + s];
    if (v > m) { acc = acc * expf(m - v) + 1.f; m = v; }
    else acc += expf(v - m);
  }
  pm[(size_t)blockIdx.y * S + s] = m;
  ps[(size_t)blockIdx.y * S + s] = acc;
}

__global__ __launch_bounds__(TPB) void col_combine(const float* __restrict__ pm, const float* __restrict__ ps,
                                                   int S, int nch,
                                                   float* __restrict__ cm, float* __restrict__ cs) {
  int s = blockIdx.x * TPB + threadIdx.x;
  if (s >= S) return;
  float m = -INFINITY, acc = 0.f;
  for (int c = 0; c < nch; ++c) {
    float m2 = pm[(size_t)c * S + s];
    float s2 = ps[(size_t)c * S + s];
    if (m2 > m) { acc = acc * expf(m - m2) + s2; m = m2; }
    else acc += s2 * expf(m2 - m);
  }
  cm[s] = m;
  cs[s] = acc;
}

// ---------------- fused row stats + finalize + argmax ----------------
// conf = exp(2v - rm - cm[j]) / (rs * cs[j])
// MODE 0: argmax only. MODE 1: write conf + argmax. MODE 2: write conf/TEMP masked (>1).
template <int MODE>
__global__ __launch_bounds__(TPB) void finalize_fused(float* __restrict__ sim, int S,
                                                      const float* __restrict__ cm,
                                                      const float* __restrict__ cs,
                                                      int* __restrict__ amax) {
  extern __shared__ float row[];
  __shared__ float red[TPB];
  __shared__ float rv[TPB];
  __shared__ int ri[TPB];
  const int l = blockIdx.x;
  float* p = sim + (size_t)l * S;
  float mt = -INFINITY, st = 0.f;
  for (int j = threadIdx.x; j < S; j += TPB) {
    float v = p[j];
    row[j] = v;
    if (v > mt) { st = st * expf(mt - v) + 1.f; mt = v; }
    else st += expf(v - mt);
  }
  red[threadIdx.x] = mt;
  __syncthreads();
  for (int stp = TPB / 2; stp > 0; stp >>= 1) {
    if (threadIdx.x < stp) red[threadIdx.x] = fmaxf(red[threadIdx.x], red[threadIdx.x + stp]);
    __syncthreads();
  }
  const float rm = red[0];
  __syncthreads();
  red[threadIdx.x] = st * expf(mt - rm);
  __syncthreads();
  for (int stp = TPB / 2; stp > 0; stp >>= 1) {
    if (threadIdx.x < stp) red[threadIdx.x] += red[threadIdx.x + stp];
    __syncthreads();
  }
  const float rs = red[0];

  float bv = -INFINITY;
  int bi = 0;
  for (int j = threadIdx.x; j < S; j += TPB) {
    float v = row[j];
    float conf = expf(2.f * v - rm - cm[j]) / (rs * cs[j]);
    if (MODE == 1) p[j] = conf;
    if (MODE == 2) {
      float c = conf * 10.f;
      p[j] = (c > 1.0f) ? c : 0.0f;
    }
    if (MODE != 2) {
      if (conf > bv) { bv = conf; bi = j; }
    }
  }
  if (MODE == 2) return;
  rv[threadIdx.x] = bv;
  ri[threadIdx.x] = bi;
  __syncthreads();
  for (int stp = TPB / 2; stp > 0; stp >>= 1) {
    if (threadIdx.x < stp) {
      float v2 = rv[threadIdx.x + stp];
      int i2 = ri[threadIdx.x + stp];
      if (v2 > rv[threadIdx.x] || (v2 == rv[threadIdx.x] && i2 < ri[threadIdx.x])) {
        rv[threadIdx.x] = v2;
        ri[threadIdx.x] = i2;
      }
    }
    __syncthreads();
  }
  if (threadIdx.x == 0) amax[l] = ri[0];
}

// ---------------- small builders ----------------
__global__ void build_x16(const float* __restrict__ t2, const float* __restrict__ f0,
                          const float* __restrict__ f1, const int* __restrict__ idx,
                          float* __restrict__ X) {
  int id = blockIdx.x * TPB + threadIdx.x;
  if (id >= 768 * 400) return;
  int c = id / 400, p = id % 400;
  float v;
  if (c < 256) v = t2[p * 256 + c];
  else if (c < 512) v = f0[p * 256 + (c - 256)];
  else v = f1[idx[p] * 256 + (c - 512)];
  X[id] = v;
}

__global__ void build_x8(const float* __restrict__ f0, const float* __restrict__ f1,
                         const int* __restrict__ idx, float* __restrict__ X) {
  int id = blockIdx.x * TPB + threadIdx.x;
  if (id >= 512 * 1600) return;
  int c = id / 1600, p = id % 1600;
  float v = (c < 256) ? f0[p * 256 + c] : f1[idx[p] * 256 + (c - 256)];
  X[id] = v;
}

__global__ void conv1x1(const float* __restrict__ W, const float* __restrict__ X,
                        float* __restrict__ Y, int O, int C, int P) {
  int id = blockIdx.x * TPB + threadIdx.x;
  if (id >= O * P) return;
  int o = id / P, p = id % P;
  float acc = 0.f;
  for (int c = 0; c < C; ++c) acc += W[o * C + c] * X[(size_t)c * P + p];
  Y[id] = acc;
}

__global__ void pool_k(const float* __restrict__ in, float* __restrict__ out, int C, int H, int f) {
  int h = H / f;
  int id = blockIdx.x * TPB + threadIdx.x;
  if (id >= C * h * h) return;
  int c = id / (h * h);
  int r = id % (h * h);
  int py = r / h, px = r % h;
  float s = 0.f;
  for (int i = 0; i < f; ++i)
    for (int j = 0; j < f; ++j)
      s += in[(size_t)c * H * H + (size_t)(py * f + i) * H + (px * f + j)];
  out[id] = s / (float)(f * f);
}

__global__ void pool14(const float* __restrict__ f0, const float* __restrict__ f1,
                       const int* __restrict__ idx, float* __restrict__ out) {
  int id = blockIdx.x * TPB + threadIdx.x;
  if (id >= 392 * 100) return;
  int c = id / 100;
  int r = id % 100;
  int py = r / 10, px = r % 10;
  float s = 0.f;
  for (int i = 0; i < 8; ++i)
    for (int j = 0; j < 8; ++j) {
      int p = (py * 8 + i) * 80 + (px * 8 + j);
      float v = (c < 196) ? f0[p * 196 + c] : f1[idx[p] * 196 + (c - 196)];
      s += v;
    }
  out[id] = s * (1.0f / 64.0f);
}

__global__ void build_xt3(const float* __restrict__ t3, const float* __restrict__ t2p,
                          const float* __restrict__ f18p, const float* __restrict__ f14p,
                          float* __restrict__ X) {
  int id = blockIdx.x * TPB + threadIdx.x;
  if (id >= 1100 * 100) return;
  int c = id / 100, p = id % 100;
  float v;
  if (c < 196) v = t3[p * 196 + c];
  else if (c < 452) v = t2p[(c - 196) * 100 + p];
  else if (c < 708) v = f18p[(c - 452) * 100 + p];
  else v = f14p[(c - 708) * 100 + p];
  X[id] = v;
}

__global__ void build_xt4(const float* __restrict__ t3d, const float* __restrict__ t4,
                          float* __restrict__ X) {
  int id = blockIdx.x * TPB + threadIdx.x;
  if (id >= 256 * 25) return;
  int c = id / 25, p = id % 25;
  X[id] = (c < 128) ? t3d[c * 25 + p] : t4[p * 128 + (c - 128)];
}

__global__ __launch_bounds__(TPB) void topic_k(const float* __restrict__ f0, const float* __restrict__ f1,
                                               const float* __restrict__ t4d, float* __restrict__ out) {
  __shared__ float s_t4[25 * 128];
  for (int i = threadIdx.x; i < 25 * 128; i += TPB) {
    int k = i >> 7, d = i & 127;
    s_t4[i] = t4d[d * 25 + k];
  }
  __syncthreads();
  int m = blockIdx.x * TPB + threadIdx.x;
  if (m >= 12800) return;
  const float* row = (m < 6400) ? (f0 + (size_t)m * 128) : (f1 + (size_t)(m - 6400) * 128);
  float acc[25];
#pragma unroll
  for (int k = 0; k < 25; ++k) acc[k] = 0.f;
  for (int d = 0; d < 128; ++d) {
    float x = row[d];
#pragma unroll
    for (int k = 0; k < 25; ++k) acc[k] += x * s_t4[k * 128 + d];
  }
  int best = 0;
  float bv = acc[0];
#pragma unroll
  for (int k = 1; k < 25; ++k)
    if (acc[k] > bv) { bv = acc[k]; best = k; }
  out[m] = (float)best;
}

extern "C" void kernel_launch(void* const* d_in, const int* in_sizes, int n_in,
                              void* d_out, int out_size, void* d_ws, size_t ws_size,
                              hipStream_t stream) {
  const float* f12_0 = (const float*)d_in[0];
  const float* f12_1 = (const float*)d_in[1];
  const float* f14_0 = (const float*)d_in[2];
  const float* f14_1 = (const float*)d_in[3];
  const float* f18_0 = (const float*)d_in[4];
  const float* f18_1 = (const float*)d_in[5];
  const float* f116_0 = (const float*)d_in[6];
  const float* f116_1 = (const float*)d_in[7];
  const float* t2 = (const float*)d_in[9];
  const float* t3 = (const float*)d_in[10];
  const float* t4 = (const float*)d_in[11];
  const float* W16 = (const float*)d_in[12];
  const float* W8 = (const float*)d_in[13];
  const float* Wt3 = (const float*)d_in[14];
  const float* Wt4 = (const float*)d_in[15];

  float* out = (float*)d_out;
  float* conf18 = out;                        // 1600*1600
  float* conf12 = out + 2560000;              // 6400*6400 (scratch for sim14, then sim12)
  float* topic = out + 2560000 + 40960000;    // 12800

  float* w = (float*)d_ws;
  auto alloc = [&](size_t n) { float* p = w; w += ((n + 63) & ~(size_t)63); return p; };

  // pack buffers (reused per-sim): max 6400 * 1216 ushorts each (15.6 MB)
  unsigned short* pA = (unsigned short*)alloc(6400 * 1216 / 2);
  unsigned short* pB = (unsigned short*)alloc(6400 * 1216 / 2);
  float* sim116 = alloc(400 * 400);
  float* cm116 = alloc(400); float* cs116 = alloc(400);
  int* idx116 = (int*)alloc(400);
  float* cm18 = alloc(1600); float* cs18 = alloc(1600);
  int* idx18 = (int*)alloc(1600);
  float* cm14 = alloc(6400); float* cs14 = alloc(6400);
  int* idx14 = (int*)alloc(6400);
  float* cm12 = alloc(6400); float* cs12 = alloc(6400);
  float* cpm = alloc(25 * 6400);
  float* cps = alloc(25 * 6400);
  float* X16 = alloc(768 * 400);
  float* t2_ = alloc(256 * 400);
  float* X8 = alloc(512 * 1600);
  float* conv18b = alloc(256 * 1600);
  float* f18p = alloc(256 * 100);
  float* t2p = alloc(256 * 100);
  float* f14p = alloc(392 * 100);
  float* Xt3 = alloc(1100 * 100);
  float* t3conv = alloc(128 * 100);
  float* t3d = alloc(128 * 25);
  float* Xt4 = alloc(256 * 25);
  float* t4d = alloc(128 * 25);

  // 6-section codes (2 bits per section, s0 = LSB): 0=hi, 1=mid, 2=lo
  // A: [h,h,m,h,l,m]  B: [h,m,h,l,h,m]  ->  hh+hm+mh+hl+lh+mm
  const int CA = 0 | (0 << 2) | (1 << 4) | (0 << 6) | (2 << 8) | (1 << 10);
  const int CB = 0 | (1 << 2) | (0 << 4) | (2 << 6) | (0 << 8) | (1 << 10);

  // ---------------- conf116 -> idx116 (D=256, K2=1536) ----------------
  {
    int L = 400, S = 400, D = 256, K2 = 1536;
    pack_split<<<cdiv(L * K2, TPB), TPB, 0, stream>>>(f116_0, pA, L, D, K2, CA);
    pack_split<<<cdiv(S * K2, TPB), TPB, 0, stream>>>(f116_1, pB, S, D, K2, CB);
    gemm_bf16_nt<<<dim3(cdiv(S, 128), cdiv(L, 128)), TPB, 0, stream>>>(pA, pB, sim116, L, S, K2);
    int nch = cdiv(L, 256);
    col_stats_part<<<dim3(cdiv(S, TPB), nch), TPB, 0, stream>>>(sim116, L, S, cpm, cps);
    col_combine<<<cdiv(S, TPB), TPB, 0, stream>>>(cpm, cps, S, nch, cm116, cs116);
    finalize_fused<0><<<L, TPB, S * 4, stream>>>(sim116, S, cm116, cs116, idx116);
  }

  build_x16<<<cdiv(768 * 400, TPB), TPB, 0, stream>>>(t2, f116_0, f116_1, idx116, X16);
  conv1x1<<<cdiv(256 * 400, TPB), TPB, 0, stream>>>(W16, X16, t2_, 256, 768, 400);

  // ---------------- conf18 (output) + idx18 (D=256, K2=1536) ----------------
  {
    int L = 1600, S = 1600, D = 256, K2 = 1536;
    pack_split<<<cdiv(L * K2, TPB), TPB, 0, stream>>>(f18_0, pA, L, D, K2, CA);
    pack_split<<<cdiv(S * K2, TPB), TPB, 0, stream>>>(f18_1, pB, S, D, K2, CB);
    gemm_bf16_nt<<<dim3(cdiv(S, 128), cdiv(L, 128)), TPB, 0, stream>>>(pA, pB, conf18, L, S, K2);
    int nch = cdiv(L, 256);
    col_stats_part<<<dim3(cdiv(S, TPB), nch), TPB, 0, stream>>>(conf18, L, S, cpm, cps);
    col_combine<<<cdiv(S, TPB), TPB, 0, stream>>>(cpm, cps, S, nch, cm18, cs18);
    finalize_fused<1><<<L, TPB, S * 4, stream>>>(conf18, S, cm18, cs18, idx18);
  }

  build_x8<<<cdiv(512 * 1600, TPB), TPB, 0, stream>>>(f18_0, f18_1, idx18, X8);
  conv1x1<<<cdiv(256 * 1600, TPB), TPB, 0, stream>>>(W8, X8, conv18b, 256, 512, 1600);
  pool_k<<<cdiv(256 * 100, TPB), TPB, 0, stream>>>(conv18b, f18p, 256, 40, 4);
  pool_k<<<cdiv(256 * 100, TPB), TPB, 0, stream>>>(t2_, t2p, 256, 20, 2);

  // ---------------- conf14 -> idx14 (D=196, K2=1216; staged in conf12 region) ----
  {
    int L = 6400, S = 6400, D = 196, K2 = 1216;
    pack_split<<<cdiv(L * K2, TPB), TPB, 0, stream>>>(f14_0, pA, L, D, K2, CA);
    pack_split<<<cdiv(S * K2, TPB), TPB, 0, stream>>>(f14_1, pB, S, D, K2, CB);
    gemm_bf16_nt<<<dim3(cdiv(S, 128), cdiv(L, 128)), TPB, 0, stream>>>(pA, pB, conf12, L, S, K2);
    int nch = cdiv(L, 256);
    col_stats_part<<<dim3(cdiv(S, TPB), nch), TPB, 0, stream>>>(conf12, L, S, cpm, cps);
    col_combine<<<cdiv(S, TPB), TPB, 0, stream>>>(cpm, cps, S, nch, cm14, cs14);
    finalize_fused<0><<<L, TPB, S * 4, stream>>>(conf12, S, cm14, cs14, idx14);
  }
  pool14<<<cdiv(392 * 100, TPB), TPB, 0, stream>>>(f14_0, f14_1, idx14, f14p);

  build_xt3<<<cdiv(1100 * 100, TPB), TPB, 0, stream>>>(t3, t2p, f18p, f14p, Xt3);
  conv1x1<<<cdiv(128 * 100, TPB), TPB, 0, stream>>>(Wt3, Xt3, t3conv, 128, 1100, 100);
  pool_k<<<cdiv(128 * 25, TPB), TPB, 0, stream>>>(t3conv, t3d, 128, 10, 2);

  build_xt4<<<cdiv(256 * 25, TPB), TPB, 0, stream>>>(t3d, t4, Xt4);
  conv1x1<<<cdiv(128 * 25, TPB), TPB, 0, stream>>>(Wt4, Xt4, t4d, 128, 256, 25);

  topic_k<<<cdiv(12800, TPB), TPB, 0, stream>>>(f12_0, f12_1, t4d, topic);

  // ---------------- conf12 (output, D=128, K2=768) ----------------
  {
    int L = 6400, S = 6400, D = 128, K2 = 768;
    pack_split<<<cdiv(L * K2, TPB), TPB, 0, stream>>>(f12_0, pA, L, D, K2, CA);
    pack_split<<<cdiv(S * K2, TPB), TPB, 0, stream>>>(f12_1, pB, S, D, K2, CB);
    gemm_bf16_nt<<<dim3(cdiv(S, 128), cdiv(L, 128)), TPB, 0, stream>>>(pA, pB, conf12, L, S, K2);
    int nch = cdiv(L, 256);
    col_stats_part<<<dim3(cdiv(S, TPB), nch), TPB, 0, stream>>>(conf12, L, S, cpm, cps);
    col_combine<<<cdiv(S, TPB), TPB, 0, stream>>>(cpm, cps, S, nch, cm12, cs12);
    finalize_fused<2><<<L, TPB, S * 4, stream>>>(conf12, S, cm12, cs12, nullptr);
  }
}

// Round 4
// 1185.468 us; speedup vs baseline: 1.5864x; 1.4297x over previous
//
#include <hip/hip_runtime.h>
#include <math.h>

#define TPB 256

typedef __attribute__((ext_vector_type(4))) float f32x4;
typedef short s16x8 __attribute__((ext_vector_type(8)));

static inline int cdiv(int a, int b) { return (a + b - 1) / b; }

#define GLOAD_LDS16(g, l)                                                        \
  __builtin_amdgcn_global_load_lds(                                              \
      (const __attribute__((address_space(1))) unsigned int*)(const void*)(g),   \
      (__attribute__((address_space(3))) unsigned int*)(void*)(l), 16, 0, 0)

__device__ __forceinline__ unsigned short f2bf_rne(float f) {
  unsigned int u = __float_as_uint(f);
  return (unsigned short)((u + 0x7FFFu + ((u >> 16) & 1u)) >> 16);
}
__device__ __forceinline__ float bf2f(unsigned short h) {
  return __uint_as_float(((unsigned int)h) << 16);
}

// ---------------- 3-term split-bf16 pack: out[m][k], section s = k/D -------
// codes: 2 bits/section: 0 = hi = bf16(a); 1 = mid = bf16(a-hi); 2 = lo = bf16(a-hi-mid).
__global__ __launch_bounds__(TPB) void pack_split(const float* __restrict__ X,
                                                  unsigned short* __restrict__ out,
                                                  int M, int D, int K2p, int codes) {
  int id = blockIdx.x * TPB + threadIdx.x;
  if (id >= M * K2p) return;
  int m = id / K2p, k = id - m * K2p;
  int s = k / D;
  unsigned short v = 0;
  if (s < 6) {
    int d = k - s * D;
    float a = X[(size_t)m * D + d];
    unsigned short h = f2bf_rne(a);
    int code = (codes >> (2 * s)) & 3;
    if (code == 0) {
      v = h;
    } else {
      float r1 = a - bf2f(h);
      unsigned short mi = f2bf_rne(r1);
      if (code == 1) v = mi;
      else v = f2bf_rne(r1 - bf2f(mi));
    }
  }
  out[id] = v;
}

// ---------------- MFMA GEMM: C(M,N) = A(M,K) * B(N,K)^T, bf16 in fp32 out ----
__global__ __launch_bounds__(TPB) void gemm_bf16_nt(const unsigned short* __restrict__ A,
                                                    const unsigned short* __restrict__ B,
                                                    float* __restrict__ C,
                                                    int M, int N, int K) {
  __shared__ __align__(16) unsigned short As[128 * 64];
  __shared__ __align__(16) unsigned short Bs[128 * 64];
  const int tid = threadIdx.x;
  const int lane = tid & 63;
  const int w = tid >> 6;
  const int wm = w >> 1, wn = w & 1;
  const int bm = blockIdx.y * 128, bn = blockIdx.x * 128;

  f32x4 acc[4][4];
#pragma unroll
  for (int m = 0; m < 4; ++m)
#pragma unroll
    for (int n = 0; n < 4; ++n) acc[m][n] = (f32x4){0.f, 0.f, 0.f, 0.f};

  const unsigned short* gA[4];
  const unsigned short* gB[4];
#pragma unroll
  for (int i = 0; i < 4; ++i) {
    int q = (w * 4 + i) * 64 + lane;
    int r = q >> 3;
    int c = (q & 7) ^ (r & 7);
    int ga = bm + r; if (ga >= M) ga = M - 1;
    int gb = bn + r; if (gb >= N) gb = N - 1;
    gA[i] = A + (size_t)ga * K + c * 8;
    gB[i] = B + (size_t)gb * K + c * 8;
  }

  for (int k0 = 0; k0 < K; k0 += 64) {
#pragma unroll
    for (int i = 0; i < 4; ++i) {
      GLOAD_LDS16(gA[i] + k0, As + (w * 4 + i) * 512);
      GLOAD_LDS16(gB[i] + k0, Bs + (w * 4 + i) * 512);
    }
    __syncthreads();
#pragma unroll
    for (int ks = 0; ks < 2; ++ks) {
      s16x8 af[4], bfr[4];
      const int c0 = ks * 4 + (lane >> 4);
#pragma unroll
      for (int m = 0; m < 4; ++m) {
        int ra = wm * 64 + m * 16 + (lane & 15);
        af[m] = *(const s16x8*)(As + ra * 64 + ((c0 ^ (ra & 7)) * 8));
        int rb = wn * 64 + m * 16 + (lane & 15);
        bfr[m] = *(const s16x8*)(Bs + rb * 64 + ((c0 ^ (rb & 7)) * 8));
      }
#pragma unroll
      for (int m = 0; m < 4; ++m)
#pragma unroll
        for (int n = 0; n < 4; ++n)
          acc[m][n] = __builtin_amdgcn_mfma_f32_16x16x32_bf16(af[m], bfr[n], acc[m][n], 0, 0, 0);
    }
    __syncthreads();
  }

#pragma unroll
  for (int m = 0; m < 4; ++m) {
    int row0 = bm + wm * 64 + m * 16 + (lane >> 4) * 4;
#pragma unroll
    for (int n = 0; n < 4; ++n) {
      int col = bn + wn * 64 + n * 16 + (lane & 15);
      if (col < N) {
#pragma unroll
        for (int j = 0; j < 4; ++j) {
          int r2 = row0 + j;
          if (r2 < M) C[(size_t)r2 * N + col] = acc[m][n][j];
        }
      }
    }
  }
}

// ---------------- per-column stats: chunked online, then combine ----------------
__global__ __launch_bounds__(TPB) void col_stats_part(const float* __restrict__ sim, int L, int S,
                                                      float* __restrict__ pm, float* __restrict__ ps) {
  int s = blockIdx.x * TPB + threadIdx.x;
  if (s >= S) return;
  int l0 = blockIdx.y * 256;
  int l1 = l0 + 256; if (l1 > L) l1 = L;
  float m = -INFINITY, acc = 0.f;
  for (int l = l0; l < l1; ++l) {
    float v = sim[(size_t)l * S + s];
    if (v > m) { acc = acc * expf(m - v) + 1.f; m = v; }
    else acc += expf(v - m);
  }
  pm[(size_t)blockIdx.y * S + s] = m;
  ps[(size_t)blockIdx.y * S + s] = acc;
}

__global__ __launch_bounds__(TPB) void col_combine(const float* __restrict__ pm, const float* __restrict__ ps,
                                                   int S, int nch,
                                                   float* __restrict__ cm, float* __restrict__ cs) {
  int s = blockIdx.x * TPB + threadIdx.x;
  if (s >= S) return;
  float m = -INFINITY, acc = 0.f;
  for (int c = 0; c < nch; ++c) {
    float m2 = pm[(size_t)c * S + s];
    float s2 = ps[(size_t)c * S + s];
    if (m2 > m) { acc = acc * expf(m - m2) + s2; m = m2; }
    else acc += s2 * expf(m2 - m);
  }
  cm[s] = m;
  cs[s] = acc;
}

// ---------------- fused row stats + finalize + argmax ----------------
template <int MODE>
__global__ __launch_bounds__(TPB) void finalize_fused(float* __restrict__ sim, int S,
                                                      const float* __restrict__ cm,
                                                      const float* __restrict__ cs,
                                                      int* __restrict__ amax) {
  extern __shared__ float row[];
  __shared__ float red[TPB];
  __shared__ float rv[TPB];
  __shared__ int ri[TPB];
  const int l = blockIdx.x;
  float* p = sim + (size_t)l * S;
  float mt = -INFINITY, st = 0.f;
  for (int j = threadIdx.x; j < S; j += TPB) {
    float v = p[j];
    row[j] = v;
    if (v > mt) { st = st * expf(mt - v) + 1.f; mt = v; }
    else st += expf(v - mt);
  }
  red[threadIdx.x] = mt;
  __syncthreads();
  for (int stp = TPB / 2; stp > 0; stp >>= 1) {
    if (threadIdx.x < stp) red[threadIdx.x] = fmaxf(red[threadIdx.x], red[threadIdx.x + stp]);
    __syncthreads();
  }
  const float rm = red[0];
  __syncthreads();
  red[threadIdx.x] = st * expf(mt - rm);
  __syncthreads();
  for (int stp = TPB / 2; stp > 0; stp >>= 1) {
    if (threadIdx.x < stp) red[threadIdx.x] += red[threadIdx.x + stp];
    __syncthreads();
  }
  const float rs = red[0];

  float bv = -INFINITY;
  int bi = 0;
  for (int j = threadIdx.x; j < S; j += TPB) {
    float v = row[j];
    float conf = expf(2.f * v - rm - cm[j]) / (rs * cs[j]);
    if (MODE == 1) p[j] = conf;
    if (MODE == 2) {
      float c = conf * 10.f;
      p[j] = (c > 1.0f) ? c : 0.0f;
    }
    if (MODE != 2) {
      if (conf > bv) { bv = conf; bi = j; }
    }
  }
  if (MODE == 2) return;
  rv[threadIdx.x] = bv;
  ri[threadIdx.x] = bi;
  __syncthreads();
  for (int stp = TPB / 2; stp > 0; stp >>= 1) {
    if (threadIdx.x < stp) {
      float v2 = rv[threadIdx.x + stp];
      int i2 = ri[threadIdx.x + stp];
      if (v2 > rv[threadIdx.x] || (v2 == rv[threadIdx.x] && i2 < ri[threadIdx.x])) {
        rv[threadIdx.x] = v2;
        ri[threadIdx.x] = i2;
      }
    }
    __syncthreads();
  }
  if (threadIdx.x == 0) amax[l] = ri[0];
}

// ---------------- small builders ----------------
__global__ void build_x16(const float* __restrict__ t2, const float* __restrict__ f0,
                          const float* __restrict__ f1, const int* __restrict__ idx,
                          float* __restrict__ X) {
  int id = blockIdx.x * TPB + threadIdx.x;
  if (id >= 768 * 400) return;
  int c = id / 400, p = id % 400;
  float v;
  if (c < 256) v = t2[p * 256 + c];
  else if (c < 512) v = f0[p * 256 + (c - 256)];
  else v = f1[idx[p] * 256 + (c - 512)];
  X[id] = v;
}

__global__ void build_x8(const float* __restrict__ f0, const float* __restrict__ f1,
                         const int* __restrict__ idx, float* __restrict__ X) {
  int id = blockIdx.x * TPB + threadIdx.x;
  if (id >= 512 * 1600) return;
  int c = id / 1600, p = id % 1600;
  float v = (c < 256) ? f0[p * 256 + c] : f1[idx[p] * 256 + (c - 256)];
  X[id] = v;
}

// ---------------- conv1x1 v2: reduction-parallel, latency-tolerant -------------
// Y(O x P) = W(O x C) * X(C x P). Block: one o, 64 p's; 256 thr = 64 p x 4 c-groups.
__global__ __launch_bounds__(TPB) void conv1x1_v2(const float* __restrict__ W,
                                                  const float* __restrict__ X,
                                                  float* __restrict__ Y,
                                                  int O, int C, int P) {
  __shared__ float red[TPB];
  const int o = blockIdx.y;
  const int pl = threadIdx.x & 63;
  const int p = blockIdx.x * 64 + pl;
  const int cg = threadIdx.x >> 6;  // 0..3
  const float* wr = W + (size_t)o * C;
  float a0 = 0.f, a1 = 0.f, a2 = 0.f, a3 = 0.f;
  if (p < P) {
    int c = cg;
    for (; c + 12 < C; c += 16) {
      a0 += wr[c]      * X[(size_t)c * P + p];
      a1 += wr[c + 4]  * X[(size_t)(c + 4) * P + p];
      a2 += wr[c + 8]  * X[(size_t)(c + 8) * P + p];
      a3 += wr[c + 12] * X[(size_t)(c + 12) * P + p];
    }
    for (; c < C; c += 4) a0 += wr[c] * X[(size_t)c * P + p];
  }
  red[threadIdx.x] = (a0 + a1) + (a2 + a3);
  __syncthreads();
  if (threadIdx.x < 64) {
    float s = (red[threadIdx.x] + red[threadIdx.x + 64]) +
              (red[threadIdx.x + 128] + red[threadIdx.x + 192]);
    if (p < P) Y[(size_t)o * P + p] = s;
  }
}

__global__ void pool_k(const float* __restrict__ in, float* __restrict__ out, int C, int H, int f) {
  int h = H / f;
  int id = blockIdx.x * TPB + threadIdx.x;
  if (id >= C * h * h) return;
  int c = id / (h * h);
  int r = id % (h * h);
  int py = r / h, px = r % h;
  float s = 0.f;
  for (int i = 0; i < f; ++i)
    for (int j = 0; j < f; ++j)
      s += in[(size_t)c * H * H + (size_t)(py * f + i) * H + (px * f + j)];
  out[id] = s / (float)(f * f);
}

__global__ void pool14(const float* __restrict__ f0, const float* __restrict__ f1,
                       const int* __restrict__ idx, float* __restrict__ out) {
  int id = blockIdx.x * TPB + threadIdx.x;
  if (id >= 392 * 100) return;
  int c = id / 100;
  int r = id % 100;
  int py = r / 10, px = r % 10;
  float s = 0.f;
  for (int i = 0; i < 8; ++i)
    for (int j = 0; j < 8; ++j) {
      int p = (py * 8 + i) * 80 + (px * 8 + j);
      float v = (c < 196) ? f0[p * 196 + c] : f1[idx[p] * 196 + (c - 196)];
      s += v;
    }
  out[id] = s * (1.0f / 64.0f);
}

__global__ void build_xt3(const float* __restrict__ t3, const float* __restrict__ t2p,
                          const float* __restrict__ f18p, const float* __restrict__ f14p,
                          float* __restrict__ X) {
  int id = blockIdx.x * TPB + threadIdx.x;
  if (id >= 1100 * 100) return;
  int c = id / 100, p = id % 100;
  float v;
  if (c < 196) v = t3[p * 196 + c];
  else if (c < 452) v = t2p[(c - 196) * 100 + p];
  else if (c < 708) v = f18p[(c - 452) * 100 + p];
  else v = f14p[(c - 708) * 100 + p];
  X[id] = v;
}

__global__ void build_xt4(const float* __restrict__ t3d, const float* __restrict__ t4,
                          float* __restrict__ X) {
  int id = blockIdx.x * TPB + threadIdx.x;
  if (id >= 256 * 25) return;
  int c = id / 25, p = id % 25;
  X[id] = (c < 128) ? t3d[c * 25 + p] : t4[p * 128 + (c - 128)];
}

__global__ __launch_bounds__(TPB) void topic_k(const float* __restrict__ f0, const float* __restrict__ f1,
                                               const float* __restrict__ t4d, float* __restrict__ out) {
  __shared__ float s_t4[25 * 128];
  for (int i = threadIdx.x; i < 25 * 128; i += TPB) {
    int k = i >> 7, d = i & 127;
    s_t4[i] = t4d[d * 25 + k];
  }
  __syncthreads();
  int m = blockIdx.x * TPB + threadIdx.x;
  if (m >= 12800) return;
  const f32x4* row = (const f32x4*)((m < 6400) ? (f0 + (size_t)m * 128)
                                               : (f1 + (size_t)(m - 6400) * 128));
  float acc[25];
#pragma unroll
  for (int k = 0; k < 25; ++k) acc[k] = 0.f;
  for (int d4 = 0; d4 < 32; ++d4) {
    f32x4 x = row[d4];
#pragma unroll
    for (int k = 0; k < 25; ++k) {
      const float* t = s_t4 + k * 128 + d4 * 4;
      acc[k] += x[0] * t[0] + x[1] * t[1] + x[2] * t[2] + x[3] * t[3];
    }
  }
  int best = 0;
  float bv = acc[0];
#pragma unroll
  for (int k = 1; k < 25; ++k)
    if (acc[k] > bv) { bv = acc[k]; best = k; }
  out[m] = (float)best;
}

extern "C" void kernel_launch(void* const* d_in, const int* in_sizes, int n_in,
                              void* d_out, int out_size, void* d_ws, size_t ws_size,
                              hipStream_t stream) {
  const float* f12_0 = (const float*)d_in[0];
  const float* f12_1 = (const float*)d_in[1];
  const float* f14_0 = (const float*)d_in[2];
  const float* f14_1 = (const float*)d_in[3];
  const float* f18_0 = (const float*)d_in[4];
  const float* f18_1 = (const float*)d_in[5];
  const float* f116_0 = (const float*)d_in[6];
  const float* f116_1 = (const float*)d_in[7];
  const float* t2 = (const float*)d_in[9];
  const float* t3 = (const float*)d_in[10];
  const float* t4 = (const float*)d_in[11];
  const float* W16 = (const float*)d_in[12];
  const float* W8 = (const float*)d_in[13];
  const float* Wt3 = (const float*)d_in[14];
  const float* Wt4 = (const float*)d_in[15];

  float* out = (float*)d_out;
  float* conf18 = out;
  float* conf12 = out + 2560000;
  float* topic = out + 2560000 + 40960000;

  float* w = (float*)d_ws;
  auto alloc = [&](size_t n) { float* p = w; w += ((n + 63) & ~(size_t)63); return p; };

  unsigned short* pA = (unsigned short*)alloc(6400 * 1216 / 2);
  unsigned short* pB = (unsigned short*)alloc(6400 * 1216 / 2);
  float* sim116 = alloc(400 * 400);
  float* cm116 = alloc(400); float* cs116 = alloc(400);
  int* idx116 = (int*)alloc(400);
  float* cm18 = alloc(1600); float* cs18 = alloc(1600);
  int* idx18 = (int*)alloc(1600);
  float* cm14 = alloc(6400); float* cs14 = alloc(6400);
  int* idx14 = (int*)alloc(6400);
  float* cm12 = alloc(6400); float* cs12 = alloc(6400);
  float* cpm = alloc(25 * 6400);
  float* cps = alloc(25 * 6400);
  float* X16 = alloc(768 * 400);
  float* t2_ = alloc(256 * 400);
  float* X8 = alloc(512 * 1600);
  float* conv18b = alloc(256 * 1600);
  float* f18p = alloc(256 * 100);
  float* t2p = alloc(256 * 100);
  float* f14p = alloc(392 * 100);
  float* Xt3 = alloc(1100 * 100);
  float* t3conv = alloc(128 * 100);
  float* t3d = alloc(128 * 25);
  float* Xt4 = alloc(256 * 25);
  float* t4d = alloc(128 * 25);

  // 6-section codes: A: [h,h,m,h,l,m]  B: [h,m,h,l,h,m]  ->  hh+hm+mh+hl+lh+mm
  const int CA = 0 | (0 << 2) | (1 << 4) | (0 << 6) | (2 << 8) | (1 << 10);
  const int CB = 0 | (1 << 2) | (0 << 4) | (2 << 6) | (0 << 8) | (1 << 10);

  // ---------------- conf116 -> idx116 (D=256, K2=1536) ----------------
  {
    int L = 400, S = 400, D = 256, K2 = 1536;
    pack_split<<<cdiv(L * K2, TPB), TPB, 0, stream>>>(f116_0, pA, L, D, K2, CA);
    pack_split<<<cdiv(S * K2, TPB), TPB, 0, stream>>>(f116_1, pB, S, D, K2, CB);
    gemm_bf16_nt<<<dim3(cdiv(S, 128), cdiv(L, 128)), TPB, 0, stream>>>(pA, pB, sim116, L, S, K2);
    int nch = cdiv(L, 256);
    col_stats_part<<<dim3(cdiv(S, TPB), nch), TPB, 0, stream>>>(sim116, L, S, cpm, cps);
    col_combine<<<cdiv(S, TPB), TPB, 0, stream>>>(cpm, cps, S, nch, cm116, cs116);
    finalize_fused<0><<<L, TPB, S * 4, stream>>>(sim116, S, cm116, cs116, idx116);
  }

  build_x16<<<cdiv(768 * 400, TPB), TPB, 0, stream>>>(t2, f116_0, f116_1, idx116, X16);
  conv1x1_v2<<<dim3(cdiv(400, 64), 256), TPB, 0, stream>>>(W16, X16, t2_, 256, 768, 400);

  // ---------------- conf18 (output) + idx18 (D=256, K2=1536) ----------------
  {
    int L = 1600, S = 1600, D = 256, K2 = 1536;
    pack_split<<<cdiv(L * K2, TPB), TPB, 0, stream>>>(f18_0, pA, L, D, K2, CA);
    pack_split<<<cdiv(S * K2, TPB), TPB, 0, stream>>>(f18_1, pB, S, D, K2, CB);
    gemm_bf16_nt<<<dim3(cdiv(S, 128), cdiv(L, 128)), TPB, 0, stream>>>(pA, pB, conf18, L, S, K2);
    int nch = cdiv(L, 256);
    col_stats_part<<<dim3(cdiv(S, TPB), nch), TPB, 0, stream>>>(conf18, L, S, cpm, cps);
    col_combine<<<cdiv(S, TPB), TPB, 0, stream>>>(cpm, cps, S, nch, cm18, cs18);
    finalize_fused<1><<<L, TPB, S * 4, stream>>>(conf18, S, cm18, cs18, idx18);
  }

  build_x8<<<cdiv(512 * 1600, TPB), TPB, 0, stream>>>(f18_0, f18_1, idx18, X8);
  conv1x1_v2<<<dim3(cdiv(1600, 64), 256), TPB, 0, stream>>>(W8, X8, conv18b, 256, 512, 1600);
  pool_k<<<cdiv(256 * 100, TPB), TPB, 0, stream>>>(conv18b, f18p, 256, 40, 4);
  pool_k<<<cdiv(256 * 100, TPB), TPB, 0, stream>>>(t2_, t2p, 256, 20, 2);

  // ---------------- conf14 -> idx14 (D=196, K2=1216; staged in conf12 region) ----
  {
    int L = 6400, S = 6400, D = 196, K2 = 1216;
    pack_split<<<cdiv(L * K2, TPB), TPB, 0, stream>>>(f14_0, pA, L, D, K2, CA);
    pack_split<<<cdiv(S * K2, TPB), TPB, 0, stream>>>(f14_1, pB, S, D, K2, CB);
    gemm_bf16_nt<<<dim3(cdiv(S, 128), cdiv(L, 128)), TPB, 0, stream>>>(pA, pB, conf12, L, S, K2);
    int nch = cdiv(L, 256);
    col_stats_part<<<dim3(cdiv(S, TPB), nch), TPB, 0, stream>>>(conf12, L, S, cpm, cps);
    col_combine<<<cdiv(S, TPB), TPB, 0, stream>>>(cpm, cps, S, nch, cm14, cs14);
    finalize_fused<0><<<L, TPB, S * 4, stream>>>(conf12, S, cm14, cs14, idx14);
  }
  pool14<<<cdiv(392 * 100, TPB), TPB, 0, stream>>>(f14_0, f14_1, idx14, f14p);

  build_xt3<<<cdiv(1100 * 100, TPB), TPB, 0, stream>>>(t3, t2p, f18p, f14p, Xt3);
  conv1x1_v2<<<dim3(cdiv(100, 64), 128), TPB, 0, stream>>>(Wt3, Xt3, t3conv, 128, 1100, 100);
  pool_k<<<cdiv(128 * 25, TPB), TPB, 0, stream>>>(t3conv, t3d, 128, 10, 2);

  build_xt4<<<cdiv(256 * 25, TPB), TPB, 0, stream>>>(t3d, t4, Xt4);
  conv1x1_v2<<<dim3(cdiv(25, 64), 128), TPB, 0, stream>>>(Wt4, Xt4, t4d, 128, 256, 25);

  topic_k<<<cdiv(12800, TPB), TPB, 0, stream>>>(f12_0, f12_1, t4d, topic);

  // ---------------- conf12 (output, D=128, K2=768) ----------------
  {
    int L = 6400, S = 6400, D = 128, K2 = 768;
    pack_split<<<cdiv(L * K2, TPB), TPB, 0, stream>>>(f12_0, pA, L, D, K2, CA);
    pack_split<<<cdiv(S * K2, TPB), TPB, 0, stream>>>(f12_1, pB, S, D, K2, CB);
    gemm_bf16_nt<<<dim3(cdiv(S, 128), cdiv(L, 128)), TPB, 0, stream>>>(pA, pB, conf12, L, S, K2);
    int nch = cdiv(L, 256);
    col_stats_part<<<dim3(cdiv(S, TPB), nch), TPB, 0, stream>>>(conf12, L, S, cpm, cps);
    col_combine<<<cdiv(S, TPB), TPB, 0, stream>>>(cpm, cps, S, nch, cm12, cs12);
    finalize_fused<2><<<L, TPB, S * 4, stream>>>(conf12, S, cm12, cs12, nullptr);
  }
}

// Round 5
// 812.546 us; speedup vs baseline: 2.3146x; 1.4590x over previous
//
#include <hip/hip_runtime.h>
#include <math.h>

#define TPB 256

typedef __attribute__((ext_vector_type(4))) float f32x4;
typedef short s16x8 __attribute__((ext_vector_type(8)));

static inline int cdiv(int a, int b) { return (a + b - 1) / b; }

#define GLOAD_LDS16(g, l)                                                        \
  __builtin_amdgcn_global_load_lds(                                              \
      (const __attribute__((address_space(1))) unsigned int*)(const void*)(g),   \
      (__attribute__((address_space(3))) unsigned int*)(void*)(l), 16, 0, 0)

__device__ __forceinline__ unsigned short f2bf_rne(float f) {
  unsigned int u = __float_as_uint(f);
  return (unsigned short)((u + 0x7FFFu + ((u >> 16) & 1u)) >> 16);
}
__device__ __forceinline__ float bf2f(unsigned short h) {
  return __uint_as_float(((unsigned int)h) << 16);
}

// ---------------- 3-term split-bf16 pack ----------------
__global__ __launch_bounds__(TPB) void pack_split(const float* __restrict__ X,
                                                  unsigned short* __restrict__ out,
                                                  int M, int D, int K2p, int codes) {
  int id = blockIdx.x * TPB + threadIdx.x;
  if (id >= M * K2p) return;
  int m = id / K2p, k = id - m * K2p;
  int s = k / D;
  unsigned short v = 0;
  if (s < 6) {
    int d = k - s * D;
    float a = X[(size_t)m * D + d];
    unsigned short h = f2bf_rne(a);
    int code = (codes >> (2 * s)) & 3;
    if (code == 0) {
      v = h;
    } else {
      float r1 = a - bf2f(h);
      unsigned short mi = f2bf_rne(r1);
      if (code == 1) v = mi;
      else v = f2bf_rne(r1 - bf2f(mi));
    }
  }
  out[id] = v;
}

// ---------------- MFMA GEMM + fused partial softmax stats -------------------
// C(M,N) = A(M,K)*B(N,K)^T. 1D grid (XCD-swizzled), 128x128 tile, 4 waves.
// Epilogue: col partials cpm/cps[by][N] (max & sumexp over this block's rows).
// If ROWSTATS: row partials rpm/rps[bx][M] over this block's cols.
template <bool ROWSTATS>
__global__ __launch_bounds__(TPB) void gemm_bf16_nt(const unsigned short* __restrict__ A,
                                                    const unsigned short* __restrict__ B,
                                                    float* __restrict__ C,
                                                    int M, int N, int K, int gx,
                                                    float* __restrict__ cpm, float* __restrict__ cps,
                                                    float* __restrict__ rpm, float* __restrict__ rps) {
  __shared__ __align__(16) unsigned short As[128 * 64];
  __shared__ __align__(16) unsigned short Bs[128 * 64];
  const int tid = threadIdx.x;
  const int lane = tid & 63;
  const int w = tid >> 6;
  const int wm = w >> 1, wn = w & 1;

  // bijective XCD swizzle (m204)
  const int nwg = gridDim.x;
  const int q = nwg >> 3, r = nwg & 7;
  const int xcd = blockIdx.x & 7, pos = blockIdx.x >> 3;
  const int wgid = (xcd < r ? xcd * (q + 1) : r * (q + 1) + (xcd - r) * q) + pos;
  const int bx = wgid % gx, by = wgid / gx;
  const int bm = by * 128, bn = bx * 128;

  f32x4 acc[4][4];
#pragma unroll
  for (int m = 0; m < 4; ++m)
#pragma unroll
    for (int n = 0; n < 4; ++n) acc[m][n] = (f32x4){0.f, 0.f, 0.f, 0.f};

  const unsigned short* gA[4];
  const unsigned short* gB[4];
#pragma unroll
  for (int i = 0; i < 4; ++i) {
    int qq = (w * 4 + i) * 64 + lane;
    int rr = qq >> 3;
    int cc = (qq & 7) ^ (rr & 7);
    int ga = bm + rr; if (ga >= M) ga = M - 1;
    int gb = bn + rr; if (gb >= N) gb = N - 1;
    gA[i] = A + (size_t)ga * K + cc * 8;
    gB[i] = B + (size_t)gb * K + cc * 8;
  }

  for (int k0 = 0; k0 < K; k0 += 64) {
#pragma unroll
    for (int i = 0; i < 4; ++i) {
      GLOAD_LDS16(gA[i] + k0, As + (w * 4 + i) * 512);
      GLOAD_LDS16(gB[i] + k0, Bs + (w * 4 + i) * 512);
    }
    __syncthreads();
#pragma unroll
    for (int ks = 0; ks < 2; ++ks) {
      s16x8 af[4], bfr[4];
      const int c0 = ks * 4 + (lane >> 4);
#pragma unroll
      for (int m = 0; m < 4; ++m) {
        int ra = wm * 64 + m * 16 + (lane & 15);
        af[m] = *(const s16x8*)(As + ra * 64 + ((c0 ^ (ra & 7)) * 8));
        int rb = wn * 64 + m * 16 + (lane & 15);
        bfr[m] = *(const s16x8*)(Bs + rb * 64 + ((c0 ^ (rb & 7)) * 8));
      }
#pragma unroll
      for (int m = 0; m < 4; ++m)
#pragma unroll
        for (int n = 0; n < 4; ++n)
          acc[m][n] = __builtin_amdgcn_mfma_f32_16x16x32_bf16(af[m], bfr[n], acc[m][n], 0, 0, 0);
    }
    __syncthreads();
  }

  // C write: col = lane&15 (+16n+64wn), row = (lane>>4)*4 + j (+16m+64wm)
#pragma unroll
  for (int m = 0; m < 4; ++m) {
    int row0 = bm + wm * 64 + m * 16 + (lane >> 4) * 4;
#pragma unroll
    for (int n = 0; n < 4; ++n) {
      int col = bn + wn * 64 + n * 16 + (lane & 15);
      if (col < N) {
#pragma unroll
        for (int j = 0; j < 4; ++j) {
          int r2 = row0 + j;
          if (r2 < M) C[(size_t)r2 * N + col] = acc[m][n][j];
        }
      }
    }
  }

  // ---- epilogue: column partials (max, sumexp over this block's 128 rows) ----
  float* scm = (float*)As;            // [8][128]
  float* sred = (float*)As + 1024;    // [128] chunk col max
  float* scs = (float*)Bs;            // [8][128]
  const int slot = wm * 4 + (lane >> 4);
#pragma unroll
  for (int n = 0; n < 4; ++n) {
    int lcol = wn * 64 + n * 16 + (lane & 15);
    float mx = -INFINITY;
#pragma unroll
    for (int m = 0; m < 4; ++m)
#pragma unroll
      for (int j = 0; j < 4; ++j) {
        int grow = bm + wm * 64 + m * 16 + (lane >> 4) * 4 + j;
        if (grow < M) mx = fmaxf(mx, acc[m][n][j]);
      }
    scm[slot * 128 + lcol] = mx;
  }
  __syncthreads();
  if (tid < 128) {
    float mx = -INFINITY;
#pragma unroll
    for (int s2 = 0; s2 < 8; ++s2) mx = fmaxf(mx, scm[s2 * 128 + tid]);
    sred[tid] = mx;
    if (bn + tid < N) cpm[(size_t)by * N + bn + tid] = mx;
  }
  __syncthreads();
#pragma unroll
  for (int n = 0; n < 4; ++n) {
    int lcol = wn * 64 + n * 16 + (lane & 15);
    float sm = sred[lcol];
    float s = 0.f;
#pragma unroll
    for (int m = 0; m < 4; ++m)
#pragma unroll
      for (int j = 0; j < 4; ++j) {
        int grow = bm + wm * 64 + m * 16 + (lane >> 4) * 4 + j;
        if (grow < M) s += expf(acc[m][n][j] - sm);
      }
    scs[slot * 128 + lcol] = s;
  }
  __syncthreads();
  if (tid < 128) {
    float s = 0.f;
#pragma unroll
    for (int s2 = 0; s2 < 8; ++s2) s += scs[s2 * 128 + tid];
    if (bn + tid < N) cps[(size_t)by * N + bn + tid] = s;
  }

  // ---- row partials (max, sumexp over this block's 128 cols) ----
  if (ROWSTATS) {
    __syncthreads();
    float* srm = (float*)As;            // [2][128]
    float* srch = (float*)As + 256;     // [128] chunk row max
    float* srs = (float*)As + 384;      // [2][128]
#pragma unroll
    for (int m = 0; m < 4; ++m)
#pragma unroll
      for (int j = 0; j < 4; ++j) {
        float mx = -INFINITY;
#pragma unroll
        for (int n = 0; n < 4; ++n) {
          int gcol = bn + wn * 64 + n * 16 + (lane & 15);
          if (gcol < N) mx = fmaxf(mx, acc[m][n][j]);
        }
#pragma unroll
        for (int d = 1; d < 16; d <<= 1) mx = fmaxf(mx, __shfl_xor(mx, d));
        if ((lane & 15) == 0) srm[wn * 128 + wm * 64 + m * 16 + (lane >> 4) * 4 + j] = mx;
      }
    __syncthreads();
    if (tid < 128) {
      float mx = fmaxf(srm[tid], srm[128 + tid]);
      srch[tid] = mx;
      if (bm + tid < M) rpm[(size_t)bx * M + bm + tid] = mx;
    }
    __syncthreads();
#pragma unroll
    for (int m = 0; m < 4; ++m)
#pragma unroll
      for (int j = 0; j < 4; ++j) {
        int lrow = wm * 64 + m * 16 + (lane >> 4) * 4 + j;
        float sm = srch[lrow];
        float s = 0.f;
#pragma unroll
        for (int n = 0; n < 4; ++n) {
          int gcol = bn + wn * 64 + n * 16 + (lane & 15);
          if (gcol < N) s += expf(acc[m][n][j] - sm);
        }
#pragma unroll
        for (int d = 1; d < 16; d <<= 1) s += __shfl_xor(s, d);
        if ((lane & 15) == 0) srs[wn * 128 + lrow] = s;
      }
    __syncthreads();
    if (tid < 128) {
      float s = srs[tid] + srs[128 + tid];
      if (bm + tid < M) rps[(size_t)bx * M + bm + tid] = s;
    }
  }
}

// ---------------- combine chunk partials ----------------
// PEN=1: o1 = m + ln(sum)  (penalty for argmax). PEN=0: o1 = m, o2 = sum.
template <int PEN>
__global__ __launch_bounds__(TPB) void stats_combine(const float* __restrict__ pm,
                                                     const float* __restrict__ ps,
                                                     int S, int nch,
                                                     float* __restrict__ o1, float* __restrict__ o2) {
  int s = blockIdx.x * TPB + threadIdx.x;
  if (s >= S) return;
  float m = -INFINITY, acc = 0.f;
  for (int c = 0; c < nch; ++c) {
    float m2 = pm[(size_t)c * S + s];
    float s2 = ps[(size_t)c * S + s];
    if (m2 > m) { acc = acc * expf(m - m2) + s2; m = m2; }
    else acc += s2 * expf(m2 - m);
  }
  if (PEN) {
    o1[s] = m + logf(acc);
  } else {
    o1[s] = m;
    o2[s] = acc;
  }
}

// ---------------- finalize variants (single pass, vectorized) ----------------
// argmax_j conf = argmax_j (2v - pen_j)  since rm, rs are row constants.
__global__ __launch_bounds__(TPB) void finalize_argmax(const float* __restrict__ sim, int S,
                                                       const float* __restrict__ pen,
                                                       int* __restrict__ amax) {
  __shared__ float rv[TPB];
  __shared__ int ri[TPB];
  const int l = blockIdx.x;
  const f32x4* row = (const f32x4*)(sim + (size_t)l * S);
  const f32x4* pv = (const f32x4*)pen;
  float bv = -INFINITY;
  int bi = 0;
  for (int j4 = threadIdx.x; j4 < (S >> 2); j4 += TPB) {
    f32x4 v = row[j4];
    f32x4 p = pv[j4];
#pragma unroll
    for (int k = 0; k < 4; ++k) {
      float sc = 2.f * v[k] - p[k];
      if (sc > bv) { bv = sc; bi = j4 * 4 + k; }
    }
  }
  rv[threadIdx.x] = bv;
  ri[threadIdx.x] = bi;
  __syncthreads();
  for (int stp = TPB / 2; stp > 0; stp >>= 1) {
    if (threadIdx.x < stp) {
      float v2 = rv[threadIdx.x + stp];
      int i2 = ri[threadIdx.x + stp];
      if (v2 > rv[threadIdx.x] || (v2 == rv[threadIdx.x] && i2 < ri[threadIdx.x])) {
        rv[threadIdx.x] = v2;
        ri[threadIdx.x] = i2;
      }
    }
    __syncthreads();
  }
  if (threadIdx.x == 0) amax[l] = ri[0];
}

// write conf + argmax (conf18)
__global__ __launch_bounds__(TPB) void finalize_write(float* __restrict__ sim, int S,
                                                      const float* __restrict__ cm,
                                                      const float* __restrict__ cs,
                                                      const float* __restrict__ rmv,
                                                      const float* __restrict__ rsv,
                                                      int* __restrict__ amax) {
  __shared__ float rv[TPB];
  __shared__ int ri[TPB];
  const int l = blockIdx.x;
  const float rm = rmv[l], rs = rsv[l];
  f32x4* row = (f32x4*)(sim + (size_t)l * S);
  const f32x4* cmv = (const f32x4*)cm;
  const f32x4* csv = (const f32x4*)cs;
  float bv = -INFINITY;
  int bi = 0;
  for (int j4 = threadIdx.x; j4 < (S >> 2); j4 += TPB) {
    f32x4 v = row[j4];
    f32x4 m2 = cmv[j4];
    f32x4 s2 = csv[j4];
    f32x4 o;
#pragma unroll
    for (int k = 0; k < 4; ++k) {
      float conf = expf(2.f * v[k] - rm - m2[k]) / (rs * s2[k]);
      o[k] = conf;
      if (conf > bv) { bv = conf; bi = j4 * 4 + k; }
    }
    row[j4] = o;
  }
  rv[threadIdx.x] = bv;
  ri[threadIdx.x] = bi;
  __syncthreads();
  for (int stp = TPB / 2; stp > 0; stp >>= 1) {
    if (threadIdx.x < stp) {
      float v2 = rv[threadIdx.x + stp];
      int i2 = ri[threadIdx.x + stp];
      if (v2 > rv[threadIdx.x] || (v2 == rv[threadIdx.x] && i2 < ri[threadIdx.x])) {
        rv[threadIdx.x] = v2;
        ri[threadIdx.x] = i2;
      }
    }
    __syncthreads();
  }
  if (threadIdx.x == 0) amax[l] = ri[0];
}

// conf12: write conf/TEMP masked (>1)
__global__ __launch_bounds__(TPB) void finalize_mask(float* __restrict__ sim, int S,
                                                     const float* __restrict__ cm,
                                                     const float* __restrict__ cs,
                                                     const float* __restrict__ rmv,
                                                     const float* __restrict__ rsv) {
  const int l = blockIdx.x;
  const float rm = rmv[l], rs = rsv[l];
  f32x4* row = (f32x4*)(sim + (size_t)l * S);
  const f32x4* cmv = (const f32x4*)cm;
  const f32x4* csv = (const f32x4*)cs;
  for (int j4 = threadIdx.x; j4 < (S >> 2); j4 += TPB) {
    f32x4 v = row[j4];
    f32x4 m2 = cmv[j4];
    f32x4 s2 = csv[j4];
    f32x4 o;
#pragma unroll
    for (int k = 0; k < 4; ++k) {
      float c = expf(2.f * v[k] - rm - m2[k]) / (rs * s2[k]) * 10.f;
      o[k] = (c > 1.0f) ? c : 0.0f;
    }
    row[j4] = o;
  }
}

// ---------------- small builders ----------------
__global__ void build_x16(const float* __restrict__ t2, const float* __restrict__ f0,
                          const float* __restrict__ f1, const int* __restrict__ idx,
                          float* __restrict__ X) {
  int id = blockIdx.x * TPB + threadIdx.x;
  if (id >= 768 * 400) return;
  int c = id / 400, p = id % 400;
  float v;
  if (c < 256) v = t2[p * 256 + c];
  else if (c < 512) v = f0[p * 256 + (c - 256)];
  else v = f1[idx[p] * 256 + (c - 512)];
  X[id] = v;
}

__global__ void build_x8(const float* __restrict__ f0, const float* __restrict__ f1,
                         const int* __restrict__ idx, float* __restrict__ X) {
  int id = blockIdx.x * TPB + threadIdx.x;
  if (id >= 512 * 1600) return;
  int c = id / 1600, p = id % 1600;
  float v = (c < 256) ? f0[p * 256 + c] : f1[idx[p] * 256 + (c - 256)];
  X[id] = v;
}

__global__ __launch_bounds__(TPB) void conv1x1_v2(const float* __restrict__ W,
                                                  const float* __restrict__ X,
                                                  float* __restrict__ Y,
                                                  int O, int C, int P) {
  __shared__ float red[TPB];
  const int o = blockIdx.y;
  const int pl = threadIdx.x & 63;
  const int p = blockIdx.x * 64 + pl;
  const int cg = threadIdx.x >> 6;
  const float* wr = W + (size_t)o * C;
  float a0 = 0.f, a1 = 0.f, a2 = 0.f, a3 = 0.f;
  if (p < P) {
    int c = cg;
    for (; c + 12 < C; c += 16) {
      a0 += wr[c]      * X[(size_t)c * P + p];
      a1 += wr[c + 4]  * X[(size_t)(c + 4) * P + p];
      a2 += wr[c + 8]  * X[(size_t)(c + 8) * P + p];
      a3 += wr[c + 12] * X[(size_t)(c + 12) * P + p];
    }
    for (; c < C; c += 4) a0 += wr[c] * X[(size_t)c * P + p];
  }
  red[threadIdx.x] = (a0 + a1) + (a2 + a3);
  __syncthreads();
  if (threadIdx.x < 64) {
    float s = (red[threadIdx.x] + red[threadIdx.x + 64]) +
              (red[threadIdx.x + 128] + red[threadIdx.x + 192]);
    if (p < P) Y[(size_t)o * P + p] = s;
  }
}

__global__ void pool_k(const float* __restrict__ in, float* __restrict__ out, int C, int H, int f) {
  int h = H / f;
  int id = blockIdx.x * TPB + threadIdx.x;
  if (id >= C * h * h) return;
  int c = id / (h * h);
  int r = id % (h * h);
  int py = r / h, px = r % h;
  float s = 0.f;
  for (int i = 0; i < f; ++i)
    for (int j = 0; j < f; ++j)
      s += in[(size_t)c * H * H + (size_t)(py * f + i) * H + (px * f + j)];
  out[id] = s / (float)(f * f);
}

__global__ void pool14(const float* __restrict__ f0, const float* __restrict__ f1,
                       const int* __restrict__ idx, float* __restrict__ out) {
  int id = blockIdx.x * TPB + threadIdx.x;
  if (id >= 392 * 100) return;
  int c = id / 100;
  int r = id % 100;
  int py = r / 10, px = r % 10;
  float s = 0.f;
  for (int i = 0; i < 8; ++i)
    for (int j = 0; j < 8; ++j) {
      int p = (py * 8 + i) * 80 + (px * 8 + j);
      float v = (c < 196) ? f0[p * 196 + c] : f1[idx[p] * 196 + (c - 196)];
      s += v;
    }
  out[id] = s * (1.0f / 64.0f);
}

__global__ void build_xt3(const float* __restrict__ t3, const float* __restrict__ t2p,
                          const float* __restrict__ f18p, const float* __restrict__ f14p,
                          float* __restrict__ X) {
  int id = blockIdx.x * TPB + threadIdx.x;
  if (id >= 1100 * 100) return;
  int c = id / 100, p = id % 100;
  float v;
  if (c < 196) v = t3[p * 196 + c];
  else if (c < 452) v = t2p[(c - 196) * 100 + p];
  else if (c < 708) v = f18p[(c - 452) * 100 + p];
  else v = f14p[(c - 708) * 100 + p];
  X[id] = v;
}

__global__ void build_xt4(const float* __restrict__ t3d, const float* __restrict__ t4,
                          float* __restrict__ X) {
  int id = blockIdx.x * TPB + threadIdx.x;
  if (id >= 256 * 25) return;
  int c = id / 25, p = id % 25;
  X[id] = (c < 128) ? t3d[c * 25 + p] : t4[p * 128 + (c - 128)];
}

__global__ __launch_bounds__(TPB) void topic_k(const float* __restrict__ f0, const float* __restrict__ f1,
                                               const float* __restrict__ t4d, float* __restrict__ out) {
  __shared__ float s_t4[25 * 128];
  for (int i = threadIdx.x; i < 25 * 128; i += TPB) {
    int k = i >> 7, d = i & 127;
    s_t4[i] = t4d[d * 25 + k];
  }
  __syncthreads();
  int m = blockIdx.x * TPB + threadIdx.x;
  if (m >= 12800) return;
  const f32x4* row = (const f32x4*)((m < 6400) ? (f0 + (size_t)m * 128)
                                               : (f1 + (size_t)(m - 6400) * 128));
  float acc[25];
#pragma unroll
  for (int k = 0; k < 25; ++k) acc[k] = 0.f;
  for (int d4 = 0; d4 < 32; ++d4) {
    f32x4 x = row[d4];
#pragma unroll
    for (int k = 0; k < 25; ++k) {
      const float* t = s_t4 + k * 128 + d4 * 4;
      acc[k] += x[0] * t[0] + x[1] * t[1] + x[2] * t[2] + x[3] * t[3];
    }
  }
  int best = 0;
  float bv = acc[0];
#pragma unroll
  for (int k = 1; k < 25; ++k)
    if (acc[k] > bv) { bv = acc[k]; best = k; }
  out[m] = (float)best;
}

extern "C" void kernel_launch(void* const* d_in, const int* in_sizes, int n_in,
                              void* d_out, int out_size, void* d_ws, size_t ws_size,
                              hipStream_t stream) {
  const float* f12_0 = (const float*)d_in[0];
  const float* f12_1 = (const float*)d_in[1];
  const float* f14_0 = (const float*)d_in[2];
  const float* f14_1 = (const float*)d_in[3];
  const float* f18_0 = (const float*)d_in[4];
  const float* f18_1 = (const float*)d_in[5];
  const float* f116_0 = (const float*)d_in[6];
  const float* f116_1 = (const float*)d_in[7];
  const float* t2 = (const float*)d_in[9];
  const float* t3 = (const float*)d_in[10];
  const float* t4 = (const float*)d_in[11];
  const float* W16 = (const float*)d_in[12];
  const float* W8 = (const float*)d_in[13];
  const float* Wt3 = (const float*)d_in[14];
  const float* Wt4 = (const float*)d_in[15];

  float* out = (float*)d_out;
  float* conf18 = out;
  float* conf12 = out + 2560000;
  float* topic = out + 2560000 + 40960000;

  float* w = (float*)d_ws;
  auto alloc = [&](size_t n) { float* p = w; w += ((n + 63) & ~(size_t)63); return p; };

  unsigned short* pA = (unsigned short*)alloc(6400 * 1216 / 2);
  unsigned short* pB = (unsigned short*)alloc(6400 * 1216 / 2);
  float* sim116 = alloc(400 * 400);
  float* pen116 = alloc(400);
  int* idx116 = (int*)alloc(400);
  float* cm18 = alloc(1600); float* cs18 = alloc(1600);
  float* rm18 = alloc(1600); float* rs18 = alloc(1600);
  int* idx18 = (int*)alloc(1600);
  float* pen14 = alloc(6400);
  int* idx14 = (int*)alloc(6400);
  float* cm12 = alloc(6400); float* cs12 = alloc(6400);
  float* rm12 = alloc(6400); float* rs12 = alloc(6400);
  float* cpm = alloc(50 * 6400);
  float* cps = alloc(50 * 6400);
  float* rpm = alloc(50 * 6400);
  float* rps = alloc(50 * 6400);
  float* X16 = alloc(768 * 400);
  float* t2_ = alloc(256 * 400);
  float* X8 = alloc(512 * 1600);
  float* conv18b = alloc(256 * 1600);
  float* f18p = alloc(256 * 100);
  float* t2p = alloc(256 * 100);
  float* f14p = alloc(392 * 100);
  float* Xt3 = alloc(1100 * 100);
  float* t3conv = alloc(128 * 100);
  float* t3d = alloc(128 * 25);
  float* Xt4 = alloc(256 * 25);
  float* t4d = alloc(128 * 25);

  // 6-section codes: A: [h,h,m,h,l,m]  B: [h,m,h,l,h,m]  ->  hh+hm+mh+hl+lh+mm
  const int CA = 0 | (0 << 2) | (1 << 4) | (0 << 6) | (2 << 8) | (1 << 10);
  const int CB = 0 | (1 << 2) | (0 << 4) | (2 << 6) | (0 << 8) | (1 << 10);

  // ---------------- conf116 -> idx116 (D=256, K2=1536) ----------------
  {
    int L = 400, S = 400, D = 256, K2 = 1536;
    int gx = cdiv(S, 128), gy = cdiv(L, 128);
    pack_split<<<cdiv(L * K2, TPB), TPB, 0, stream>>>(f116_0, pA, L, D, K2, CA);
    pack_split<<<cdiv(S * K2, TPB), TPB, 0, stream>>>(f116_1, pB, S, D, K2, CB);
    gemm_bf16_nt<false><<<gx * gy, TPB, 0, stream>>>(pA, pB, sim116, L, S, K2, gx,
                                                     cpm, cps, nullptr, nullptr);
    stats_combine<1><<<cdiv(S, TPB), TPB, 0, stream>>>(cpm, cps, S, gy, pen116, nullptr);
    finalize_argmax<<<L, TPB, 0, stream>>>(sim116, S, pen116, idx116);
  }

  build_x16<<<cdiv(768 * 400, TPB), TPB, 0, stream>>>(t2, f116_0, f116_1, idx116, X16);
  conv1x1_v2<<<dim3(cdiv(400, 64), 256), TPB, 0, stream>>>(W16, X16, t2_, 256, 768, 400);

  // ---------------- conf18 (output) + idx18 (D=256, K2=1536) ----------------
  {
    int L = 1600, S = 1600, D = 256, K2 = 1536;
    int gx = cdiv(S, 128), gy = cdiv(L, 128);
    pack_split<<<cdiv(L * K2, TPB), TPB, 0, stream>>>(f18_0, pA, L, D, K2, CA);
    pack_split<<<cdiv(S * K2, TPB), TPB, 0, stream>>>(f18_1, pB, S, D, K2, CB);
    gemm_bf16_nt<true><<<gx * gy, TPB, 0, stream>>>(pA, pB, conf18, L, S, K2, gx,
                                                    cpm, cps, rpm, rps);
    stats_combine<0><<<cdiv(S, TPB), TPB, 0, stream>>>(cpm, cps, S, gy, cm18, cs18);
    stats_combine<0><<<cdiv(L, TPB), TPB, 0, stream>>>(rpm, rps, L, gx, rm18, rs18);
    finalize_write<<<L, TPB, 0, stream>>>(conf18, S, cm18, cs18, rm18, rs18, idx18);
  }

  build_x8<<<cdiv(512 * 1600, TPB), TPB, 0, stream>>>(f18_0, f18_1, idx18, X8);
  conv1x1_v2<<<dim3(cdiv(1600, 64), 256), TPB, 0, stream>>>(W8, X8, conv18b, 256, 512, 1600);
  pool_k<<<cdiv(256 * 100, TPB), TPB, 0, stream>>>(conv18b, f18p, 256, 40, 4);
  pool_k<<<cdiv(256 * 100, TPB), TPB, 0, stream>>>(t2_, t2p, 256, 20, 2);

  // ---------------- conf14 -> idx14 (D=196, K2=1216; staged in conf12 region) ----
  {
    int L = 6400, S = 6400, D = 196, K2 = 1216;
    int gx = cdiv(S, 128), gy = cdiv(L, 128);
    pack_split<<<cdiv(L * K2, TPB), TPB, 0, stream>>>(f14_0, pA, L, D, K2, CA);
    pack_split<<<cdiv(S * K2, TPB), TPB, 0, stream>>>(f14_1, pB, S, D, K2, CB);
    gemm_bf16_nt<false><<<gx * gy, TPB, 0, stream>>>(pA, pB, conf12, L, S, K2, gx,
                                                     cpm, cps, nullptr, nullptr);
    stats_combine<1><<<cdiv(S, TPB), TPB, 0, stream>>>(cpm, cps, S, gy, pen14, nullptr);
    finalize_argmax<<<L, TPB, 0, stream>>>(conf12, S, pen14, idx14);
  }
  pool14<<<cdiv(392 * 100, TPB), TPB, 0, stream>>>(f14_0, f14_1, idx14, f14p);

  build_xt3<<<cdiv(1100 * 100, TPB), TPB, 0, stream>>>(t3, t2p, f18p, f14p, Xt3);
  conv1x1_v2<<<dim3(cdiv(100, 64), 128), TPB, 0, stream>>>(Wt3, Xt3, t3conv, 128, 1100, 100);
  pool_k<<<cdiv(128 * 25, TPB), TPB, 0, stream>>>(t3conv, t3d, 128, 10, 2);

  build_xt4<<<cdiv(256 * 25, TPB), TPB, 0, stream>>>(t3d, t4, Xt4);
  conv1x1_v2<<<dim3(cdiv(25, 64), 128), TPB, 0, stream>>>(Wt4, Xt4, t4d, 128, 256, 25);

  topic_k<<<cdiv(12800, TPB), TPB, 0, stream>>>(f12_0, f12_1, t4d, topic);

  // ---------------- conf12 (output, D=128, K2=768) ----------------
  {
    int L = 6400, S = 6400, D = 128, K2 = 768;
    int gx = cdiv(S, 128), gy = cdiv(L, 128);
    pack_split<<<cdiv(L * K2, TPB), TPB, 0, stream>>>(f12_0, pA, L, D, K2, CA);
    pack_split<<<cdiv(S * K2, TPB), TPB, 0, stream>>>(f12_1, pB, S, D, K2, CB);
    gemm_bf16_nt<true><<<gx * gy, TPB, 0, stream>>>(pA, pB, conf12, L, S, K2, gx,
                                                    cpm, cps, rpm, rps);
    stats_combine<0><<<cdiv(S, TPB), TPB, 0, stream>>>(cpm, cps, S, gy, cm12, cs12);
    stats_combine<0><<<cdiv(L, TPB), TPB, 0, stream>>>(rpm, rps, L, gx, rm12, rs12);
    finalize_mask<<<L, TPB, 0, stream>>>(conf12, S, cm12, cs12, rm12, rs12);
  }
}

// Round 6
// 696.692 us; speedup vs baseline: 2.6994x; 1.1663x over previous
//
#include <hip/hip_runtime.h>
#include <math.h>

#define TPB 256
#define C0F 20.0f

typedef __attribute__((ext_vector_type(4))) float f32x4;
typedef short s16x8 __attribute__((ext_vector_type(8)));

static inline int cdiv(int a, int b) { return (a + b - 1) / b; }

#define GLOAD_LDS16(g, l)                                                        \
  __builtin_amdgcn_global_load_lds(                                              \
      (const __attribute__((address_space(1))) unsigned int*)(const void*)(g),   \
      (__attribute__((address_space(3))) unsigned int*)(void*)(l), 16, 0, 0)

__device__ __forceinline__ unsigned short f2bf_rne(float f) {
  unsigned int u = __float_as_uint(f);
  return (unsigned short)((u + 0x7FFFu + ((u >> 16) & 1u)) >> 16);
}
__device__ __forceinline__ float bf2f(unsigned short h) {
  return __uint_as_float(((unsigned int)h) << 16);
}

// ---------------- 3-term split-bf16 pack ----------------
__global__ __launch_bounds__(TPB) void pack_split(const float* __restrict__ X,
                                                  unsigned short* __restrict__ out,
                                                  int M, int D, int K2p, int codes) {
  int id = blockIdx.x * TPB + threadIdx.x;
  if (id >= M * K2p) return;
  int m = id / K2p, k = id - m * K2p;
  int s = k / D;
  unsigned short v = 0;
  if (s < 6) {
    int d = k - s * D;
    float a = X[(size_t)m * D + d];
    unsigned short h = f2bf_rne(a);
    int code = (codes >> (2 * s)) & 3;
    if (code == 0) {
      v = h;
    } else {
      float r1 = a - bf2f(h);
      unsigned short mi = f2bf_rne(r1);
      if (code == 1) v = mi;
      else v = f2bf_rne(r1 - bf2f(mi));
    }
  }
  out[id] = v;
}

// ---------------- MFMA GEMM + fused exp-sum partials -------------------
// C(M,N) = A(M,K)*B(N,K)^T. Writes raw C, plus col partials cps[by][N] =
// sum_rows exp(v - C0); if ROWSTATS also rps[bx][M] = sum_cols exp(v - C0).
// EXACT: M, N multiples of 128 (no bounds checks anywhere).
template <bool EXACT, bool ROWSTATS>
__global__ __launch_bounds__(TPB) void gemm_bf16_nt(const unsigned short* __restrict__ A,
                                                    const unsigned short* __restrict__ B,
                                                    float* __restrict__ C,
                                                    int M, int N, int K, int gx, int gy,
                                                    float* __restrict__ cps,
                                                    float* __restrict__ rps) {
  __shared__ __align__(16) unsigned short As[128 * 64];
  __shared__ __align__(16) unsigned short Bs[128 * 64];
  const int tid = threadIdx.x;
  const int lane = tid & 63;
  const int w = tid >> 6;
  const int wm = w >> 1, wn = w & 1;

  // bijective XCD swizzle (m204) + grouped tile order (8 tile-rows/group)
  const int nwg = gridDim.x;
  const int q = nwg >> 3, r = nwg & 7;
  const int xcd = blockIdx.x & 7, pos = blockIdx.x >> 3;
  const int wgid = (xcd < r ? xcd * (q + 1) : r * (q + 1) + (xcd - r) * q) + pos;
  const int tpg = 8 * gx;
  const int g = wgid / tpg;
  const int rem = wgid - g * tpg;
  const int rows = min(8, gy - g * 8);
  const int bx = rem / rows;
  const int by = g * 8 + rem - bx * rows;
  const int bm = by * 128, bn = bx * 128;

  f32x4 acc[4][4];
#pragma unroll
  for (int m = 0; m < 4; ++m)
#pragma unroll
    for (int n = 0; n < 4; ++n) acc[m][n] = (f32x4){0.f, 0.f, 0.f, 0.f};

  const unsigned short* gA[4];
  const unsigned short* gB[4];
#pragma unroll
  for (int i = 0; i < 4; ++i) {
    int qq = (w * 4 + i) * 64 + lane;
    int rr = qq >> 3;
    int cc = (qq & 7) ^ (rr & 7);
    int ga = bm + rr, gb = bn + rr;
    if (!EXACT) { if (ga >= M) ga = M - 1; if (gb >= N) gb = N - 1; }
    gA[i] = A + (size_t)ga * K + cc * 8;
    gB[i] = B + (size_t)gb * K + cc * 8;
  }

  for (int k0 = 0; k0 < K; k0 += 64) {
#pragma unroll
    for (int i = 0; i < 4; ++i) {
      GLOAD_LDS16(gA[i] + k0, As + (w * 4 + i) * 512);
      GLOAD_LDS16(gB[i] + k0, Bs + (w * 4 + i) * 512);
    }
    __syncthreads();
#pragma unroll
    for (int ks = 0; ks < 2; ++ks) {
      s16x8 af[4], bfr[4];
      const int c0 = ks * 4 + (lane >> 4);
#pragma unroll
      for (int m = 0; m < 4; ++m) {
        int ra = wm * 64 + m * 16 + (lane & 15);
        af[m] = *(const s16x8*)(As + ra * 64 + ((c0 ^ (ra & 7)) * 8));
        int rb = wn * 64 + m * 16 + (lane & 15);
        bfr[m] = *(const s16x8*)(Bs + rb * 64 + ((c0 ^ (rb & 7)) * 8));
      }
#pragma unroll
      for (int m = 0; m < 4; ++m)
#pragma unroll
        for (int n = 0; n < 4; ++n)
          acc[m][n] = __builtin_amdgcn_mfma_f32_16x16x32_bf16(af[m], bfr[n], acc[m][n], 0, 0, 0);
    }
    __syncthreads();
  }

  // C write: col = lane&15 (+16n+64wn), row = (lane>>4)*4 + j (+16m+64wm)
#pragma unroll
  for (int m = 0; m < 4; ++m) {
    int row0 = bm + wm * 64 + m * 16 + (lane >> 4) * 4;
#pragma unroll
    for (int n = 0; n < 4; ++n) {
      int col = bn + wn * 64 + n * 16 + (lane & 15);
      if (EXACT || col < N) {
#pragma unroll
        for (int j = 0; j < 4; ++j) {
          int r2 = row0 + j;
          if (EXACT || r2 < M) C[(size_t)r2 * N + col] = acc[m][n][j];
        }
      }
    }
  }

  // ---- acc := exp(acc - C0) in place ----
#pragma unroll
  for (int m = 0; m < 4; ++m)
#pragma unroll
    for (int n = 0; n < 4; ++n)
#pragma unroll
      for (int j = 0; j < 4; ++j) acc[m][n][j] = __expf(acc[m][n][j] - C0F);

  // ---- col partials: sum over this block's 128 rows ----
  float* scs = (float*)As;  // [8][128]
  const int slot = wm * 4 + (lane >> 4);
#pragma unroll
  for (int n = 0; n < 4; ++n) {
    int lcol = wn * 64 + n * 16 + (lane & 15);
    float s = 0.f;
#pragma unroll
    for (int m = 0; m < 4; ++m)
#pragma unroll
      for (int j = 0; j < 4; ++j) {
        if (!EXACT) {
          int grow = bm + wm * 64 + m * 16 + (lane >> 4) * 4 + j;
          if (grow >= M) continue;
        }
        s += acc[m][n][j];
      }
    scs[slot * 128 + lcol] = s;
  }
  __syncthreads();
  if (tid < 128) {
    float s = 0.f;
#pragma unroll
    for (int k = 0; k < 8; ++k) s += scs[k * 128 + tid];
    if (EXACT || bn + tid < N) cps[(size_t)by * N + bn + tid] = s;
  }

  // ---- row partials: sum over this block's 128 cols ----
  if (ROWSTATS) {
    float* srs = (float*)Bs;  // [2][128]
#pragma unroll
    for (int m = 0; m < 4; ++m)
#pragma unroll
      for (int j = 0; j < 4; ++j) {
        float s = 0.f;
#pragma unroll
        for (int n = 0; n < 4; ++n) {
          if (!EXACT) {
            int gcol = bn + wn * 64 + n * 16 + (lane & 15);
            if (gcol >= N) continue;
          }
          s += acc[m][n][j];
        }
#pragma unroll
        for (int d = 1; d < 16; d <<= 1) s += __shfl_xor(s, d);
        if ((lane & 15) == 0) srs[wn * 128 + wm * 64 + m * 16 + (lane >> 4) * 4 + j] = s;
      }
    __syncthreads();
    if (tid < 128) {
      float s = srs[tid] + srs[128 + tid];
      if (EXACT || bm + tid < M) rps[(size_t)bx * M + bm + tid] = s;
    }
  }
}

// ---------------- combine: out[s] = ln(sum of chunk partials) ----------------
__global__ __launch_bounds__(TPB) void logsum_combine(const float* __restrict__ ps,
                                                      int S, int nch,
                                                      float* __restrict__ out) {
  int s = blockIdx.x * TPB + threadIdx.x;
  if (s >= S) return;
  float a = 0.f;
  for (int c = 0; c < nch; ++c) a += ps[(size_t)c * S + s];
  out[s] = logf(a);
}

// ---------------- finalize variants ----------------
// argmax_j conf = argmax_j (2v - pen_j); pen = col log-sum (offset version).
__global__ __launch_bounds__(TPB) void finalize_argmax(const float* __restrict__ sim, int S,
                                                       const float* __restrict__ pen,
                                                       int* __restrict__ amax) {
  __shared__ float rv[TPB];
  __shared__ int ri[TPB];
  const int l = blockIdx.x;
  const f32x4* row = (const f32x4*)(sim + (size_t)l * S);
  const f32x4* pv = (const f32x4*)pen;
  float bv = -INFINITY;
  int bi = 0;
  for (int j4 = threadIdx.x; j4 < (S >> 2); j4 += TPB) {
    f32x4 v = row[j4];
    f32x4 p = pv[j4];
#pragma unroll
    for (int k = 0; k < 4; ++k) {
      float sc = 2.f * v[k] - p[k];
      if (sc > bv) { bv = sc; bi = j4 * 4 + k; }
    }
  }
  rv[threadIdx.x] = bv;
  ri[threadIdx.x] = bi;
  __syncthreads();
  for (int stp = TPB / 2; stp > 0; stp >>= 1) {
    if (threadIdx.x < stp) {
      float v2 = rv[threadIdx.x + stp];
      int i2 = ri[threadIdx.x + stp];
      if (v2 > rv[threadIdx.x] || (v2 == rv[threadIdx.x] && i2 < ri[threadIdx.x])) {
        rv[threadIdx.x] = v2;
        ri[threadIdx.x] = i2;
      }
    }
    __syncthreads();
  }
  if (threadIdx.x == 0) amax[l] = ri[0];
}

// conf18: conf = exp(2v - cls_j - rls_l - 2*C0); write + argmax
__global__ __launch_bounds__(TPB) void finalize_write(float* __restrict__ sim, int S,
                                                      const float* __restrict__ cls,
                                                      const float* __restrict__ rls,
                                                      int* __restrict__ amax) {
  __shared__ float rv[TPB];
  __shared__ int ri[TPB];
  const int l = blockIdx.x;
  const float rl = rls[l] + 2.0f * C0F;
  f32x4* row = (f32x4*)(sim + (size_t)l * S);
  const f32x4* cv = (const f32x4*)cls;
  float bv = -INFINITY;
  int bi = 0;
  for (int j4 = threadIdx.x; j4 < (S >> 2); j4 += TPB) {
    f32x4 v = row[j4];
    f32x4 cl = cv[j4];
    f32x4 o;
#pragma unroll
    for (int k = 0; k < 4; ++k) {
      float conf = expf(2.f * v[k] - cl[k] - rl);
      o[k] = conf;
      if (conf > bv) { bv = conf; bi = j4 * 4 + k; }
    }
    row[j4] = o;
  }
  rv[threadIdx.x] = bv;
  ri[threadIdx.x] = bi;
  __syncthreads();
  for (int stp = TPB / 2; stp > 0; stp >>= 1) {
    if (threadIdx.x < stp) {
      float v2 = rv[threadIdx.x + stp];
      int i2 = ri[threadIdx.x + stp];
      if (v2 > rv[threadIdx.x] || (v2 == rv[threadIdx.x] && i2 < ri[threadIdx.x])) {
        rv[threadIdx.x] = v2;
        ri[threadIdx.x] = i2;
      }
    }
    __syncthreads();
  }
  if (threadIdx.x == 0) amax[l] = ri[0];
}

// conf12: c = conf*10 = exp(2v - cls_j - rls_l - 2*C0 + ln10); write c if c>1 else 0
__global__ __launch_bounds__(TPB) void finalize_mask(float* __restrict__ sim, int S,
                                                     const float* __restrict__ cls,
                                                     const float* __restrict__ rls) {
  const int l = blockIdx.x;
  const float rl = rls[l] + 2.0f * C0F - 2.302585093f;  // -ln(10)
  f32x4* row = (f32x4*)(sim + (size_t)l * S);
  const f32x4* cv = (const f32x4*)cls;
  for (int j4 = threadIdx.x; j4 < (S >> 2); j4 += TPB) {
    f32x4 v = row[j4];
    f32x4 cl = cv[j4];
    f32x4 o;
#pragma unroll
    for (int k = 0; k < 4; ++k) {
      float c = expf(2.f * v[k] - cl[k] - rl);
      o[k] = (c > 1.0f) ? c : 0.0f;
    }
    row[j4] = o;
  }
}

// ---------------- small builders ----------------
__global__ void build_x16(const float* __restrict__ t2, const float* __restrict__ f0,
                          const float* __restrict__ f1, const int* __restrict__ idx,
                          float* __restrict__ X) {
  int id = blockIdx.x * TPB + threadIdx.x;
  if (id >= 768 * 400) return;
  int c = id / 400, p = id % 400;
  float v;
  if (c < 256) v = t2[p * 256 + c];
  else if (c < 512) v = f0[p * 256 + (c - 256)];
  else v = f1[idx[p] * 256 + (c - 512)];
  X[id] = v;
}

__global__ void build_x8(const float* __restrict__ f0, const float* __restrict__ f1,
                         const int* __restrict__ idx, float* __restrict__ X) {
  int id = blockIdx.x * TPB + threadIdx.x;
  if (id >= 512 * 1600) return;
  int c = id / 1600, p = id % 1600;
  float v = (c < 256) ? f0[p * 256 + c] : f1[idx[p] * 256 + (c - 256)];
  X[id] = v;
}

__global__ __launch_bounds__(TPB) void conv1x1_v2(const float* __restrict__ W,
                                                  const float* __restrict__ X,
                                                  float* __restrict__ Y,
                                                  int O, int C, int P) {
  __shared__ float red[TPB];
  const int o = blockIdx.y;
  const int pl = threadIdx.x & 63;
  const int p = blockIdx.x * 64 + pl;
  const int cg = threadIdx.x >> 6;
  const float* wr = W + (size_t)o * C;
  float a0 = 0.f, a1 = 0.f, a2 = 0.f, a3 = 0.f;
  if (p < P) {
    int c = cg;
    for (; c + 12 < C; c += 16) {
      a0 += wr[c]      * X[(size_t)c * P + p];
      a1 += wr[c + 4]  * X[(size_t)(c + 4) * P + p];
      a2 += wr[c + 8]  * X[(size_t)(c + 8) * P + p];
      a3 += wr[c + 12] * X[(size_t)(c + 12) * P + p];
    }
    for (; c < C; c += 4) a0 += wr[c] * X[(size_t)c * P + p];
  }
  red[threadIdx.x] = (a0 + a1) + (a2 + a3);
  __syncthreads();
  if (threadIdx.x < 64) {
    float s = (red[threadIdx.x] + red[threadIdx.x + 64]) +
              (red[threadIdx.x + 128] + red[threadIdx.x + 192]);
    if (p < P) Y[(size_t)o * P + p] = s;
  }
}

__global__ void pool_k(const float* __restrict__ in, float* __restrict__ out, int C, int H, int f) {
  int h = H / f;
  int id = blockIdx.x * TPB + threadIdx.x;
  if (id >= C * h * h) return;
  int c = id / (h * h);
  int r = id % (h * h);
  int py = r / h, px = r % h;
  float s = 0.f;
  for (int i = 0; i < f; ++i)
    for (int j = 0; j < f; ++j)
      s += in[(size_t)c * H * H + (size_t)(py * f + i) * H + (px * f + j)];
  out[id] = s / (float)(f * f);
}

__global__ void pool14(const float* __restrict__ f0, const float* __restrict__ f1,
                       const int* __restrict__ idx, float* __restrict__ out) {
  int id = blockIdx.x * TPB + threadIdx.x;
  if (id >= 392 * 100) return;
  int c = id / 100;
  int r = id % 100;
  int py = r / 10, px = r % 10;
  float s = 0.f;
  for (int i = 0; i < 8; ++i)
    for (int j = 0; j < 8; ++j) {
      int p = (py * 8 + i) * 80 + (px * 8 + j);
      float v = (c < 196) ? f0[p * 196 + c] : f1[idx[p] * 196 + (c - 196)];
      s += v;
    }
  out[id] = s * (1.0f / 64.0f);
}

__global__ void build_xt3(const float* __restrict__ t3, const float* __restrict__ t2p,
                          const float* __restrict__ f18p, const float* __restrict__ f14p,
                          float* __restrict__ X) {
  int id = blockIdx.x * TPB + threadIdx.x;
  if (id >= 1100 * 100) return;
  int c = id / 100, p = id % 100;
  float v;
  if (c < 196) v = t3[p * 196 + c];
  else if (c < 452) v = t2p[(c - 196) * 100 + p];
  else if (c < 708) v = f18p[(c - 452) * 100 + p];
  else v = f14p[(c - 708) * 100 + p];
  X[id] = v;
}

__global__ void build_xt4(const float* __restrict__ t3d, const float* __restrict__ t4,
                          float* __restrict__ X) {
  int id = blockIdx.x * TPB + threadIdx.x;
  if (id >= 256 * 25) return;
  int c = id / 25, p = id % 25;
  X[id] = (c < 128) ? t3d[c * 25 + p] : t4[p * 128 + (c - 128)];
}

__global__ __launch_bounds__(TPB) void topic_k(const float* __restrict__ f0, const float* __restrict__ f1,
                                               const float* __restrict__ t4d, float* __restrict__ out) {
  __shared__ float s_t4[25 * 128];
  for (int i = threadIdx.x; i < 25 * 128; i += TPB) {
    int k = i >> 7, d = i & 127;
    s_t4[i] = t4d[d * 25 + k];
  }
  __syncthreads();
  int m = blockIdx.x * TPB + threadIdx.x;
  if (m >= 12800) return;
  const f32x4* row = (const f32x4*)((m < 6400) ? (f0 + (size_t)m * 128)
                                               : (f1 + (size_t)(m - 6400) * 128));
  float acc[25];
#pragma unroll
  for (int k = 0; k < 25; ++k) acc[k] = 0.f;
  for (int d4 = 0; d4 < 32; ++d4) {
    f32x4 x = row[d4];
#pragma unroll
    for (int k = 0; k < 25; ++k) {
      const float* t = s_t4 + k * 128 + d4 * 4;
      acc[k] += x[0] * t[0] + x[1] * t[1] + x[2] * t[2] + x[3] * t[3];
    }
  }
  int best = 0;
  float bv = acc[0];
#pragma unroll
  for (int k = 1; k < 25; ++k)
    if (acc[k] > bv) { bv = acc[k]; best = k; }
  out[m] = (float)best;
}

extern "C" void kernel_launch(void* const* d_in, const int* in_sizes, int n_in,
                              void* d_out, int out_size, void* d_ws, size_t ws_size,
                              hipStream_t stream) {
  const float* f12_0 = (const float*)d_in[0];
  const float* f12_1 = (const float*)d_in[1];
  const float* f14_0 = (const float*)d_in[2];
  const float* f14_1 = (const float*)d_in[3];
  const float* f18_0 = (const float*)d_in[4];
  const float* f18_1 = (const float*)d_in[5];
  const float* f116_0 = (const float*)d_in[6];
  const float* f116_1 = (const float*)d_in[7];
  const float* t2 = (const float*)d_in[9];
  const float* t3 = (const float*)d_in[10];
  const float* t4 = (const float*)d_in[11];
  const float* W16 = (const float*)d_in[12];
  const float* W8 = (const float*)d_in[13];
  const float* Wt3 = (const float*)d_in[14];
  const float* Wt4 = (const float*)d_in[15];

  float* out = (float*)d_out;
  float* conf18 = out;
  float* conf12 = out + 2560000;
  float* topic = out + 2560000 + 40960000;

  float* w = (float*)d_ws;
  auto alloc = [&](size_t n) { float* p = w; w += ((n + 63) & ~(size_t)63); return p; };

  unsigned short* pA = (unsigned short*)alloc(6400 * 1216 / 2);
  unsigned short* pB = (unsigned short*)alloc(6400 * 1216 / 2);
  float* sim116 = alloc(400 * 400);
  float* pen116 = alloc(400);
  int* idx116 = (int*)alloc(400);
  float* cls18 = alloc(1600); float* rls18 = alloc(1600);
  int* idx18 = (int*)alloc(1600);
  float* pen14 = alloc(6400);
  int* idx14 = (int*)alloc(6400);
  float* cls12 = alloc(6400); float* rls12 = alloc(6400);
  float* cps = alloc(50 * 6400);
  float* rps = alloc(50 * 6400);
  float* X16 = alloc(768 * 400);
  float* t2_ = alloc(256 * 400);
  float* X8 = alloc(512 * 1600);
  float* conv18b = alloc(256 * 1600);
  float* f18p = alloc(256 * 100);
  float* t2p = alloc(256 * 100);
  float* f14p = alloc(392 * 100);
  float* Xt3 = alloc(1100 * 100);
  float* t3conv = alloc(128 * 100);
  float* t3d = alloc(128 * 25);
  float* Xt4 = alloc(256 * 25);
  float* t4d = alloc(128 * 25);

  // 6-section codes: A: [h,h,m,h,l,m]  B: [h,m,h,l,h,m]  ->  hh+hm+mh+hl+lh+mm
  const int CA = 0 | (0 << 2) | (1 << 4) | (0 << 6) | (2 << 8) | (1 << 10);
  const int CB = 0 | (1 << 2) | (0 << 4) | (2 << 6) | (0 << 8) | (1 << 10);

  // ---------------- conf116 -> idx116 (D=256, K2=1536) ----------------
  {
    int L = 400, S = 400, K2 = 1536;
    int gx = cdiv(S, 128), gy = cdiv(L, 128);
    pack_split<<<cdiv(L * K2, TPB), TPB, 0, stream>>>(f116_0, pA, L, 256, K2, CA);
    pack_split<<<cdiv(S * K2, TPB), TPB, 0, stream>>>(f116_1, pB, S, 256, K2, CB);
    gemm_bf16_nt<false, false><<<gx * gy, TPB, 0, stream>>>(pA, pB, sim116, L, S, K2, gx, gy,
                                                            cps, nullptr);
    logsum_combine<<<cdiv(S, TPB), TPB, 0, stream>>>(cps, S, gy, pen116);
    finalize_argmax<<<L, TPB, 0, stream>>>(sim116, S, pen116, idx116);
  }

  build_x16<<<cdiv(768 * 400, TPB), TPB, 0, stream>>>(t2, f116_0, f116_1, idx116, X16);
  conv1x1_v2<<<dim3(cdiv(400, 64), 256), TPB, 0, stream>>>(W16, X16, t2_, 256, 768, 400);

  // ---------------- conf18 (output) + idx18 (D=256, K2=1536) ----------------
  {
    int L = 1600, S = 1600, K2 = 1536;
    int gx = cdiv(S, 128), gy = cdiv(L, 128);
    pack_split<<<cdiv(L * K2, TPB), TPB, 0, stream>>>(f18_0, pA, L, 256, K2, CA);
    pack_split<<<cdiv(S * K2, TPB), TPB, 0, stream>>>(f18_1, pB, S, 256, K2, CB);
    gemm_bf16_nt<false, true><<<gx * gy, TPB, 0, stream>>>(pA, pB, conf18, L, S, K2, gx, gy,
                                                           cps, rps);
    logsum_combine<<<cdiv(S, TPB), TPB, 0, stream>>>(cps, S, gy, cls18);
    logsum_combine<<<cdiv(L, TPB), TPB, 0, stream>>>(rps, L, gx, rls18);
    finalize_write<<<L, TPB, 0, stream>>>(conf18, S, cls18, rls18, idx18);
  }

  build_x8<<<cdiv(512 * 1600, TPB), TPB, 0, stream>>>(f18_0, f18_1, idx18, X8);
  conv1x1_v2<<<dim3(cdiv(1600, 64), 256), TPB, 0, stream>>>(W8, X8, conv18b, 256, 512, 1600);
  pool_k<<<cdiv(256 * 100, TPB), TPB, 0, stream>>>(conv18b, f18p, 256, 40, 4);
  pool_k<<<cdiv(256 * 100, TPB), TPB, 0, stream>>>(t2_, t2p, 256, 20, 2);

  // ---------------- conf14 -> idx14 (D=196, K2=1216; staged in conf12 region) ----
  {
    int L = 6400, S = 6400, K2 = 1216;
    int gx = cdiv(S, 128), gy = cdiv(L, 128);
    pack_split<<<cdiv(L * K2, TPB), TPB, 0, stream>>>(f14_0, pA, L, 196, K2, CA);
    pack_split<<<cdiv(S * K2, TPB), TPB, 0, stream>>>(f14_1, pB, S, 196, K2, CB);
    gemm_bf16_nt<true, false><<<gx * gy, TPB, 0, stream>>>(pA, pB, conf12, L, S, K2, gx, gy,
                                                           cps, nullptr);
    logsum_combine<<<cdiv(S, TPB), TPB, 0, stream>>>(cps, S, gy, pen14);
    finalize_argmax<<<L, TPB, 0, stream>>>(conf12, S, pen14, idx14);
  }
  pool14<<<cdiv(392 * 100, TPB), TPB, 0, stream>>>(f14_0, f14_1, idx14, f14p);

  build_xt3<<<cdiv(1100 * 100, TPB), TPB, 0, stream>>>(t3, t2p, f18p, f14p, Xt3);
  conv1x1_v2<<<dim3(cdiv(100, 64), 128), TPB, 0, stream>>>(Wt3, Xt3, t3conv, 128, 1100, 100);
  pool_k<<<cdiv(128 * 25, TPB), TPB, 0, stream>>>(t3conv, t3d, 128, 10, 2);

  build_xt4<<<cdiv(256 * 25, TPB), TPB, 0, stream>>>(t3d, t4, Xt4);
  conv1x1_v2<<<dim3(cdiv(25, 64), 128), TPB, 0, stream>>>(Wt4, Xt4, t4d, 128, 256, 25);

  topic_k<<<cdiv(12800, TPB), TPB, 0, stream>>>(f12_0, f12_1, t4d, topic);

  // ---------------- conf12 (output, D=128, K2=768) ----------------
  {
    int L = 6400, S = 6400, K2 = 768;
    int gx = cdiv(S, 128), gy = cdiv(L, 128);
    pack_split<<<cdiv(L * K2, TPB), TPB, 0, stream>>>(f12_0, pA, L, 128, K2, CA);
    pack_split<<<cdiv(S * K2, TPB), TPB, 0, stream>>>(f12_1, pB, S, 128, K2, CB);
    gemm_bf16_nt<true, true><<<gx * gy, TPB, 0, stream>>>(pA, pB, conf12, L, S, K2, gx, gy,
                                                          cps, rps);
    logsum_combine<<<cdiv(S, TPB), TPB, 0, stream>>>(cps, S, gy, cls12);
    logsum_combine<<<cdiv(L, TPB), TPB, 0, stream>>>(rps, L, gx, rls12);
    finalize_mask<<<L, TPB, 0, stream>>>(conf12, S, cls12, rls12);
  }
}

// Round 7
// 610.879 us; speedup vs baseline: 3.0786x; 1.1405x over previous
//
#include <hip/hip_runtime.h>
#include <math.h>

#define TPB 256
#define C0F 20.0f

typedef __attribute__((ext_vector_type(4))) float f32x4;
typedef short s16x8 __attribute__((ext_vector_type(8)));

static inline int cdiv(int a, int b) { return (a + b - 1) / b; }

#define GLOAD_LDS16(g, l)                                                        \
  __builtin_amdgcn_global_load_lds(                                              \
      (const __attribute__((address_space(1))) unsigned int*)(const void*)(g),   \
      (__attribute__((address_space(3))) unsigned int*)(void*)(l), 16, 0, 0)

__device__ __forceinline__ unsigned short f2bf_rne(float f) {
  unsigned int u = __float_as_uint(f);
  return (unsigned short)((u + 0x7FFFu + ((u >> 16) & 1u)) >> 16);
}
__device__ __forceinline__ float bf2f(unsigned short h) {
  return __uint_as_float(((unsigned int)h) << 16);
}

// ---------------- 3-term split-bf16 pack, A and B in one launch -------------
__global__ __launch_bounds__(TPB) void pack_split2(const float* __restrict__ XA,
                                                   const float* __restrict__ XB,
                                                   unsigned short* __restrict__ outA,
                                                   unsigned short* __restrict__ outB,
                                                   int M, int D, int K2p,
                                                   int codesA, int codesB) {
  int id = blockIdx.x * TPB + threadIdx.x;
  if (id >= M * K2p) return;
  const float* X = blockIdx.y ? XB : XA;
  unsigned short* out = blockIdx.y ? outB : outA;
  int codes = blockIdx.y ? codesB : codesA;
  int m = id / K2p, k = id - m * K2p;
  int s = k / D;
  unsigned short v = 0;
  if (s < 6) {
    int d = k - s * D;
    float a = X[(size_t)m * D + d];
    unsigned short h = f2bf_rne(a);
    int code = (codes >> (2 * s)) & 3;
    if (code == 0) {
      v = h;
    } else {
      float r1 = a - bf2f(h);
      unsigned short mi = f2bf_rne(r1);
      if (code == 1) v = mi;
      else v = f2bf_rne(r1 - bf2f(mi));
    }
  }
  out[id] = v;
}

// ---------------- small-GEMM (128x128, 4 waves) + fused exp-sum partials ----
template <bool EXACT, bool ROWSTATS>
__global__ __launch_bounds__(TPB) void gemm_bf16_nt(const unsigned short* __restrict__ A,
                                                    const unsigned short* __restrict__ B,
                                                    float* __restrict__ C,
                                                    int M, int N, int K, int gx, int gy,
                                                    float* __restrict__ cps,
                                                    float* __restrict__ rps) {
  __shared__ __align__(16) unsigned short As[128 * 64];
  __shared__ __align__(16) unsigned short Bs[128 * 64];
  const int tid = threadIdx.x;
  const int lane = tid & 63;
  const int w = tid >> 6;
  const int wm = w >> 1, wn = w & 1;

  const int nwg = gridDim.x;
  const int q = nwg >> 3, r = nwg & 7;
  const int xcd = blockIdx.x & 7, pos = blockIdx.x >> 3;
  const int wgid = (xcd < r ? xcd * (q + 1) : r * (q + 1) + (xcd - r) * q) + pos;
  const int tpg = 8 * gx;
  const int g = wgid / tpg;
  const int rem = wgid - g * tpg;
  const int rows = min(8, gy - g * 8);
  const int bx = rem / rows;
  const int by = g * 8 + rem - bx * rows;
  const int bm = by * 128, bn = bx * 128;

  f32x4 acc[4][4];
#pragma unroll
  for (int m = 0; m < 4; ++m)
#pragma unroll
    for (int n = 0; n < 4; ++n) acc[m][n] = (f32x4){0.f, 0.f, 0.f, 0.f};

  const unsigned short* gA[4];
  const unsigned short* gB[4];
#pragma unroll
  for (int i = 0; i < 4; ++i) {
    int qq = (w * 4 + i) * 64 + lane;
    int rr = qq >> 3;
    int cc = (qq & 7) ^ (rr & 7);
    int ga = bm + rr, gb = bn + rr;
    if (!EXACT) { if (ga >= M) ga = M - 1; if (gb >= N) gb = N - 1; }
    gA[i] = A + (size_t)ga * K + cc * 8;
    gB[i] = B + (size_t)gb * K + cc * 8;
  }

  for (int k0 = 0; k0 < K; k0 += 64) {
#pragma unroll
    for (int i = 0; i < 4; ++i) {
      GLOAD_LDS16(gA[i] + k0, As + (w * 4 + i) * 512);
      GLOAD_LDS16(gB[i] + k0, Bs + (w * 4 + i) * 512);
    }
    __syncthreads();
#pragma unroll
    for (int ks = 0; ks < 2; ++ks) {
      s16x8 af[4], bfr[4];
      const int c0 = ks * 4 + (lane >> 4);
#pragma unroll
      for (int m = 0; m < 4; ++m) {
        int ra = wm * 64 + m * 16 + (lane & 15);
        af[m] = *(const s16x8*)(As + ra * 64 + ((c0 ^ (ra & 7)) * 8));
        int rb = wn * 64 + m * 16 + (lane & 15);
        bfr[m] = *(const s16x8*)(Bs + rb * 64 + ((c0 ^ (rb & 7)) * 8));
      }
#pragma unroll
      for (int m = 0; m < 4; ++m)
#pragma unroll
        for (int n = 0; n < 4; ++n)
          acc[m][n] = __builtin_amdgcn_mfma_f32_16x16x32_bf16(af[m], bfr[n], acc[m][n], 0, 0, 0);
    }
    __syncthreads();
  }

#pragma unroll
  for (int m = 0; m < 4; ++m) {
    int row0 = bm + wm * 64 + m * 16 + (lane >> 4) * 4;
#pragma unroll
    for (int n = 0; n < 4; ++n) {
      int col = bn + wn * 64 + n * 16 + (lane & 15);
      if (EXACT || col < N) {
#pragma unroll
        for (int j = 0; j < 4; ++j) {
          int r2 = row0 + j;
          if (EXACT || r2 < M) C[(size_t)r2 * N + col] = acc[m][n][j];
        }
      }
    }
  }

#pragma unroll
  for (int m = 0; m < 4; ++m)
#pragma unroll
    for (int n = 0; n < 4; ++n)
#pragma unroll
      for (int j = 0; j < 4; ++j) acc[m][n][j] = __expf(acc[m][n][j] - C0F);

  float* scs = (float*)As;  // [8][128]
  const int slot = wm * 4 + (lane >> 4);
#pragma unroll
  for (int n = 0; n < 4; ++n) {
    int lcol = wn * 64 + n * 16 + (lane & 15);
    float s = 0.f;
#pragma unroll
    for (int m = 0; m < 4; ++m)
#pragma unroll
      for (int j = 0; j < 4; ++j) {
        if (!EXACT) {
          int grow = bm + wm * 64 + m * 16 + (lane >> 4) * 4 + j;
          if (grow >= M) continue;
        }
        s += acc[m][n][j];
      }
    scs[slot * 128 + lcol] = s;
  }
  __syncthreads();
  if (tid < 128) {
    float s = 0.f;
#pragma unroll
    for (int k = 0; k < 8; ++k) s += scs[k * 128 + tid];
    if (EXACT || bn + tid < N) cps[(size_t)by * N + bn + tid] = s;
  }

  if (ROWSTATS) {
    float* srs = (float*)Bs;  // [2][128]
#pragma unroll
    for (int m = 0; m < 4; ++m)
#pragma unroll
      for (int j = 0; j < 4; ++j) {
        float s = 0.f;
#pragma unroll
        for (int n = 0; n < 4; ++n) {
          if (!EXACT) {
            int gcol = bn + wn * 64 + n * 16 + (lane & 15);
            if (gcol >= N) continue;
          }
          s += acc[m][n][j];
        }
#pragma unroll
        for (int d = 1; d < 16; d <<= 1) s += __shfl_xor(s, d);
        if ((lane & 15) == 0) srs[wn * 128 + wm * 64 + m * 16 + (lane >> 4) * 4 + j] = s;
      }
    __syncthreads();
    if (tid < 128) {
      float s = srs[tid] + srs[128 + tid];
      if (EXACT || bm + tid < M) rps[(size_t)bx * M + bm + tid] = s;
    }
  }
}

// ---------------- big-GEMM (128x256, 8 waves, EXACT) + fused partials -------
// M mult of 128, N mult of 256. Wave grid 2(m) x 4(n), each wave 64x64.
template <bool ROWSTATS>
__global__ __launch_bounds__(512) void gemm_big(const unsigned short* __restrict__ A,
                                                const unsigned short* __restrict__ B,
                                                float* __restrict__ C,
                                                int M, int N, int K, int gx, int gy,
                                                float* __restrict__ cps,
                                                float* __restrict__ rps) {
  __shared__ __align__(16) unsigned short As[128 * 64];   // 16 KB
  __shared__ __align__(16) unsigned short Bs[256 * 64];   // 32 KB
  const int tid = threadIdx.x;
  const int lane = tid & 63;
  const int w = tid >> 6;          // 0..7
  const int wm = w >> 2, wn = w & 3;

  const int nwg = gridDim.x;
  const int q = nwg >> 3, r = nwg & 7;
  const int xcd = blockIdx.x & 7, pos = blockIdx.x >> 3;
  const int wgid = (xcd < r ? xcd * (q + 1) : r * (q + 1) + (xcd - r) * q) + pos;
  const int tpg = 8 * gx;
  const int g = wgid / tpg;
  const int rem = wgid - g * tpg;
  const int rows = min(8, gy - g * 8);
  const int bx = rem / rows;
  const int by = g * 8 + rem - bx * rows;
  const int bm = by * 128, bn = bx * 256;

  f32x4 acc[4][4];
#pragma unroll
  for (int m = 0; m < 4; ++m)
#pragma unroll
    for (int n = 0; n < 4; ++n) acc[m][n] = (f32x4){0.f, 0.f, 0.f, 0.f};

  // staging: A has 1024 16B-chunks (2/thread), B has 2048 (4/thread).
  // LDS slot q = r*8 + cp holds global chunk c = cp ^ (r&7) of row r.
  const unsigned short* gA[2];
  const unsigned short* gB[4];
#pragma unroll
  for (int i = 0; i < 2; ++i) {
    int qq = i * 512 + tid;
    int rr = qq >> 3;
    int cc = (qq & 7) ^ (rr & 7);
    gA[i] = A + (size_t)(bm + rr) * K + cc * 8;
  }
#pragma unroll
  for (int i = 0; i < 4; ++i) {
    int qq = i * 512 + tid;
    int rr = qq >> 3;
    int cc = (qq & 7) ^ (rr & 7);
    gB[i] = B + (size_t)(bn + rr) * K + cc * 8;
  }

  for (int k0 = 0; k0 < K; k0 += 64) {
#pragma unroll
    for (int i = 0; i < 2; ++i)
      GLOAD_LDS16(gA[i] + k0, As + (i * 8 + w) * 512);
#pragma unroll
    for (int i = 0; i < 4; ++i)
      GLOAD_LDS16(gB[i] + k0, Bs + (i * 8 + w) * 512);
    __syncthreads();
#pragma unroll
    for (int ks = 0; ks < 2; ++ks) {
      s16x8 af[4], bfr[4];
      const int c0 = ks * 4 + (lane >> 4);
#pragma unroll
      for (int m = 0; m < 4; ++m) {
        int ra = wm * 64 + m * 16 + (lane & 15);
        af[m] = *(const s16x8*)(As + ra * 64 + ((c0 ^ (ra & 7)) * 8));
        int rb = wn * 64 + m * 16 + (lane & 15);
        bfr[m] = *(const s16x8*)(Bs + rb * 64 + ((c0 ^ (rb & 7)) * 8));
      }
#pragma unroll
      for (int m = 0; m < 4; ++m)
#pragma unroll
        for (int n = 0; n < 4; ++n)
          acc[m][n] = __builtin_amdgcn_mfma_f32_16x16x32_bf16(af[m], bfr[n], acc[m][n], 0, 0, 0);
    }
    __syncthreads();
  }

  // C write
#pragma unroll
  for (int m = 0; m < 4; ++m) {
    int row0 = bm + wm * 64 + m * 16 + (lane >> 4) * 4;
#pragma unroll
    for (int n = 0; n < 4; ++n) {
      int col = bn + wn * 64 + n * 16 + (lane & 15);
#pragma unroll
      for (int j = 0; j < 4; ++j)
        C[(size_t)(row0 + j) * N + col] = acc[m][n][j];
    }
  }

#pragma unroll
  for (int m = 0; m < 4; ++m)
#pragma unroll
    for (int n = 0; n < 4; ++n)
#pragma unroll
      for (int j = 0; j < 4; ++j) acc[m][n][j] = __expf(acc[m][n][j] - C0F);

  // col partials over this block's 128 rows: 256 cols, 8 contributing slots
  float* scs = (float*)As;  // [8][256] = 8 KB
  const int slot = wm * 4 + (lane >> 4);
#pragma unroll
  for (int n = 0; n < 4; ++n) {
    int lcol = wn * 64 + n * 16 + (lane & 15);
    float s = 0.f;
#pragma unroll
    for (int m = 0; m < 4; ++m)
#pragma unroll
      for (int j = 0; j < 4; ++j) s += acc[m][n][j];
    scs[slot * 256 + lcol] = s;
  }
  __syncthreads();
  if (tid < 256) {
    float s = 0.f;
#pragma unroll
    for (int k = 0; k < 8; ++k) s += scs[k * 256 + tid];
    cps[(size_t)by * N + bn + tid] = s;
  }

  // row partials over this block's 256 cols: 128 rows, 4 contributing waves
  if (ROWSTATS) {
    float* srs = (float*)Bs;  // [4][128] = 2 KB
#pragma unroll
    for (int m = 0; m < 4; ++m)
#pragma unroll
      for (int j = 0; j < 4; ++j) {
        float s = 0.f;
#pragma unroll
        for (int n = 0; n < 4; ++n) s += acc[m][n][j];
#pragma unroll
        for (int d = 1; d < 16; d <<= 1) s += __shfl_xor(s, d);
        if ((lane & 15) == 0) srs[wn * 128 + wm * 64 + m * 16 + (lane >> 4) * 4 + j] = s;
      }
    __syncthreads();
    if (tid < 128) {
      float s = (srs[tid] + srs[128 + tid]) + (srs[256 + tid] + srs[384 + tid]);
      rps[(size_t)bx * M + bm + tid] = s;
    }
  }
}

// ---------------- combine: out[s] = ln(sum of chunk partials) ----------------
// grid.y==0: col partials (nch_c) -> out_c ; grid.y==1: row partials (nch_r) -> out_r
__global__ __launch_bounds__(TPB) void logsum_combine2(const float* __restrict__ cps,
                                                       const float* __restrict__ rps,
                                                       int S, int nch_c, int nch_r,
                                                       float* __restrict__ out_c,
                                                       float* __restrict__ out_r) {
  int s = blockIdx.x * TPB + threadIdx.x;
  if (s >= S) return;
  const float* ps = blockIdx.y ? rps : cps;
  int nch = blockIdx.y ? nch_r : nch_c;
  float a = 0.f;
  for (int c = 0; c < nch; ++c) a += ps[(size_t)c * S + s];
  (blockIdx.y ? out_r : out_c)[s] = logf(a);
}

// ---------------- finalize variants ----------------
__global__ __launch_bounds__(TPB) void finalize_argmax(const float* __restrict__ sim, int S,
                                                       const float* __restrict__ pen,
                                                       int* __restrict__ amax) {
  __shared__ float rv[TPB];
  __shared__ int ri[TPB];
  const int l = blockIdx.x;
  const f32x4* row = (const f32x4*)(sim + (size_t)l * S);
  const f32x4* pv = (const f32x4*)pen;
  float bv = -INFINITY;
  int bi = 0;
  for (int j4 = threadIdx.x; j4 < (S >> 2); j4 += TPB) {
    f32x4 v = row[j4];
    f32x4 p = pv[j4];
#pragma unroll
    for (int k = 0; k < 4; ++k) {
      float sc = 2.f * v[k] - p[k];
      if (sc > bv) { bv = sc; bi = j4 * 4 + k; }
    }
  }
  rv[threadIdx.x] = bv;
  ri[threadIdx.x] = bi;
  __syncthreads();
  for (int stp = TPB / 2; stp > 0; stp >>= 1) {
    if (threadIdx.x < stp) {
      float v2 = rv[threadIdx.x + stp];
      int i2 = ri[threadIdx.x + stp];
      if (v2 > rv[threadIdx.x] || (v2 == rv[threadIdx.x] && i2 < ri[threadIdx.x])) {
        rv[threadIdx.x] = v2;
        ri[threadIdx.x] = i2;
      }
    }
    __syncthreads();
  }
  if (threadIdx.x == 0) amax[l] = ri[0];
}

__global__ __launch_bounds__(TPB) void finalize_write(float* __restrict__ sim, int S,
                                                      const float* __restrict__ cls,
                                                      const float* __restrict__ rls,
                                                      int* __restrict__ amax) {
  __shared__ float rv[TPB];
  __shared__ int ri[TPB];
  const int l = blockIdx.x;
  const float rl = rls[l] + 2.0f * C0F;
  f32x4* row = (f32x4*)(sim + (size_t)l * S);
  const f32x4* cv = (const f32x4*)cls;
  float bv = -INFINITY;
  int bi = 0;
  for (int j4 = threadIdx.x; j4 < (S >> 2); j4 += TPB) {
    f32x4 v = row[j4];
    f32x4 cl = cv[j4];
    f32x4 o;
#pragma unroll
    for (int k = 0; k < 4; ++k) {
      float conf = expf(2.f * v[k] - cl[k] - rl);
      o[k] = conf;
      if (conf > bv) { bv = conf; bi = j4 * 4 + k; }
    }
    row[j4] = o;
  }
  rv[threadIdx.x] = bv;
  ri[threadIdx.x] = bi;
  __syncthreads();
  for (int stp = TPB / 2; stp > 0; stp >>= 1) {
    if (threadIdx.x < stp) {
      float v2 = rv[threadIdx.x + stp];
      int i2 = ri[threadIdx.x + stp];
      if (v2 > rv[threadIdx.x] || (v2 == rv[threadIdx.x] && i2 < ri[threadIdx.x])) {
        rv[threadIdx.x] = v2;
        ri[threadIdx.x] = i2;
      }
    }
    __syncthreads();
  }
  if (threadIdx.x == 0) amax[l] = ri[0];
}

__global__ __launch_bounds__(TPB) void finalize_mask(float* __restrict__ sim, int S,
                                                     const float* __restrict__ cls,
                                                     const float* __restrict__ rls) {
  const int l = blockIdx.x;
  const float rl = rls[l] + 2.0f * C0F - 2.302585093f;  // -ln(10)
  f32x4* row = (f32x4*)(sim + (size_t)l * S);
  const f32x4* cv = (const f32x4*)cls;
  for (int j4 = threadIdx.x; j4 < (S >> 2); j4 += TPB) {
    f32x4 v = row[j4];
    f32x4 cl = cv[j4];
    f32x4 o;
#pragma unroll
    for (int k = 0; k < 4; ++k) {
      float c = expf(2.f * v[k] - cl[k] - rl);
      o[k] = (c > 1.0f) ? c : 0.0f;
    }
    row[j4] = o;
  }
}

// ---------------- small builders ----------------
__global__ void build_x16(const float* __restrict__ t2, const float* __restrict__ f0,
                          const float* __restrict__ f1, const int* __restrict__ idx,
                          float* __restrict__ X) {
  int id = blockIdx.x * TPB + threadIdx.x;
  if (id >= 768 * 400) return;
  int c = id / 400, p = id % 400;
  float v;
  if (c < 256) v = t2[p * 256 + c];
  else if (c < 512) v = f0[p * 256 + (c - 256)];
  else v = f1[idx[p] * 256 + (c - 512)];
  X[id] = v;
}

__global__ void build_x8(const float* __restrict__ f0, const float* __restrict__ f1,
                         const int* __restrict__ idx, float* __restrict__ X) {
  int id = blockIdx.x * TPB + threadIdx.x;
  if (id >= 512 * 1600) return;
  int c = id / 1600, p = id % 1600;
  float v = (c < 256) ? f0[p * 256 + c] : f1[idx[p] * 256 + (c - 256)];
  X[id] = v;
}

__global__ __launch_bounds__(TPB) void conv1x1_v2(const float* __restrict__ W,
                                                  const float* __restrict__ X,
                                                  float* __restrict__ Y,
                                                  int O, int C, int P) {
  __shared__ float red[TPB];
  const int o = blockIdx.y;
  const int pl = threadIdx.x & 63;
  const int p = blockIdx.x * 64 + pl;
  const int cg = threadIdx.x >> 6;
  const float* wr = W + (size_t)o * C;
  float a0 = 0.f, a1 = 0.f, a2 = 0.f, a3 = 0.f;
  if (p < P) {
    int c = cg;
    for (; c + 12 < C; c += 16) {
      a0 += wr[c]      * X[(size_t)c * P + p];
      a1 += wr[c + 4]  * X[(size_t)(c + 4) * P + p];
      a2 += wr[c + 8]  * X[(size_t)(c + 8) * P + p];
      a3 += wr[c + 12] * X[(size_t)(c + 12) * P + p];
    }
    for (; c < C; c += 4) a0 += wr[c] * X[(size_t)c * P + p];
  }
  red[threadIdx.x] = (a0 + a1) + (a2 + a3);
  __syncthreads();
  if (threadIdx.x < 64) {
    float s = (red[threadIdx.x] + red[threadIdx.x + 64]) +
              (red[threadIdx.x + 128] + red[threadIdx.x + 192]);
    if (p < P) Y[(size_t)o * P + p] = s;
  }
}

__global__ void pool_k(const float* __restrict__ in, float* __restrict__ out, int C, int H, int f) {
  int h = H / f;
  int id = blockIdx.x * TPB + threadIdx.x;
  if (id >= C * h * h) return;
  int c = id / (h * h);
  int r = id % (h * h);
  int py = r / h, px = r % h;
  float s = 0.f;
  for (int i = 0; i < f; ++i)
    for (int j = 0; j < f; ++j)
      s += in[(size_t)c * H * H + (size_t)(py * f + i) * H + (px * f + j)];
  out[id] = s / (float)(f * f);
}

__global__ void pool14(const float* __restrict__ f0, const float* __restrict__ f1,
                       const int* __restrict__ idx, float* __restrict__ out) {
  int id = blockIdx.x * TPB + threadIdx.x;
  if (id >= 392 * 100) return;
  int c = id / 100;
  int r = id % 100;
  int py = r / 10, px = r % 10;
  float s = 0.f;
  for (int i = 0; i < 8; ++i)
    for (int j = 0; j < 8; ++j) {
      int p = (py * 8 + i) * 80 + (px * 8 + j);
      float v = (c < 196) ? f0[p * 196 + c] : f1[idx[p] * 196 + (c - 196)];
      s += v;
    }
  out[id] = s * (1.0f / 64.0f);
}

__global__ void build_xt3(const float* __restrict__ t3, const float* __restrict__ t2p,
                          const float* __restrict__ f18p, const float* __restrict__ f14p,
                          float* __restrict__ X) {
  int id = blockIdx.x * TPB + threadIdx.x;
  if (id >= 1100 * 100) return;
  int c = id / 100, p = id % 100;
  float v;
  if (c < 196) v = t3[p * 196 + c];
  else if (c < 452) v = t2p[(c - 196) * 100 + p];
  else if (c < 708) v = f18p[(c - 452) * 100 + p];
  else v = f14p[(c - 708) * 100 + p];
  X[id] = v;
}

__global__ void build_xt4(const float* __restrict__ t3d, const float* __restrict__ t4,
                          float* __restrict__ X) {
  int id = blockIdx.x * TPB + threadIdx.x;
  if (id >= 256 * 25) return;
  int c = id / 25, p = id % 25;
  X[id] = (c < 128) ? t3d[c * 25 + p] : t4[p * 128 + (c - 128)];
}

__global__ __launch_bounds__(TPB) void topic_k(const float* __restrict__ f0, const float* __restrict__ f1,
                                               const float* __restrict__ t4d, float* __restrict__ out) {
  __shared__ float s_t4[25 * 128];
  for (int i = threadIdx.x; i < 25 * 128; i += TPB) {
    int k = i >> 7, d = i & 127;
    s_t4[i] = t4d[d * 25 + k];
  }
  __syncthreads();
  int m = blockIdx.x * TPB + threadIdx.x;
  if (m >= 12800) return;
  const f32x4* row = (const f32x4*)((m < 6400) ? (f0 + (size_t)m * 128)
                                               : (f1 + (size_t)(m - 6400) * 128));
  float acc[25];
#pragma unroll
  for (int k = 0; k < 25; ++k) acc[k] = 0.f;
  for (int d4 = 0; d4 < 32; ++d4) {
    f32x4 x = row[d4];
#pragma unroll
    for (int k = 0; k < 25; ++k) {
      const float* t = s_t4 + k * 128 + d4 * 4;
      acc[k] += x[0] * t[0] + x[1] * t[1] + x[2] * t[2] + x[3] * t[3];
    }
  }
  int best = 0;
  float bv = acc[0];
#pragma unroll
  for (int k = 1; k < 25; ++k)
    if (acc[k] > bv) { bv = acc[k]; best = k; }
  out[m] = (float)best;
}

extern "C" void kernel_launch(void* const* d_in, const int* in_sizes, int n_in,
                              void* d_out, int out_size, void* d_ws, size_t ws_size,
                              hipStream_t stream) {
  const float* f12_0 = (const float*)d_in[0];
  const float* f12_1 = (const float*)d_in[1];
  const float* f14_0 = (const float*)d_in[2];
  const float* f14_1 = (const float*)d_in[3];
  const float* f18_0 = (const float*)d_in[4];
  const float* f18_1 = (const float*)d_in[5];
  const float* f116_0 = (const float*)d_in[6];
  const float* f116_1 = (const float*)d_in[7];
  const float* t2 = (const float*)d_in[9];
  const float* t3 = (const float*)d_in[10];
  const float* t4 = (const float*)d_in[11];
  const float* W16 = (const float*)d_in[12];
  const float* W8 = (const float*)d_in[13];
  const float* Wt3 = (const float*)d_in[14];
  const float* Wt4 = (const float*)d_in[15];

  float* out = (float*)d_out;
  float* conf18 = out;
  float* conf12 = out + 2560000;
  float* topic = out + 2560000 + 40960000;

  float* w = (float*)d_ws;
  auto alloc = [&](size_t n) { float* p = w; w += ((n + 63) & ~(size_t)63); return p; };

  unsigned short* pA = (unsigned short*)alloc(6400 * 1216 / 2);
  unsigned short* pB = (unsigned short*)alloc(6400 * 1216 / 2);
  float* sim116 = alloc(400 * 400);
  float* pen116 = alloc(400);
  int* idx116 = (int*)alloc(400);
  float* cls18 = alloc(1600); float* rls18 = alloc(1600);
  int* idx18 = (int*)alloc(1600);
  float* pen14 = alloc(6400);
  int* idx14 = (int*)alloc(6400);
  float* cls12 = alloc(6400); float* rls12 = alloc(6400);
  float* cps = alloc(50 * 6400);
  float* rps = alloc(50 * 6400);
  float* X16 = alloc(768 * 400);
  float* t2_ = alloc(256 * 400);
  float* X8 = alloc(512 * 1600);
  float* conv18b = alloc(256 * 1600);
  float* f18p = alloc(256 * 100);
  float* t2p = alloc(256 * 100);
  float* f14p = alloc(392 * 100);
  float* Xt3 = alloc(1100 * 100);
  float* t3conv = alloc(128 * 100);
  float* t3d = alloc(128 * 25);
  float* Xt4 = alloc(256 * 25);
  float* t4d = alloc(128 * 25);

  // 6-section codes: A: [h,h,m,h,l,m]  B: [h,m,h,l,h,m]  ->  hh+hm+mh+hl+lh+mm
  const int CA = 0 | (0 << 2) | (1 << 4) | (0 << 6) | (2 << 8) | (1 << 10);
  const int CB = 0 | (1 << 2) | (0 << 4) | (2 << 6) | (0 << 8) | (1 << 10);

  // ---------------- conf116 -> idx116 (D=256, K2=1536) ----------------
  {
    int L = 400, S = 400, K2 = 1536;
    int gx = cdiv(S, 128), gy = cdiv(L, 128);
    pack_split2<<<dim3(cdiv(L * K2, TPB), 2), TPB, 0, stream>>>(f116_0, f116_1, pA, pB, L, 256, K2, CA, CB);
    gemm_bf16_nt<false, false><<<gx * gy, TPB, 0, stream>>>(pA, pB, sim116, L, S, K2, gx, gy,
                                                            cps, nullptr);
    logsum_combine2<<<dim3(cdiv(S, TPB), 1), TPB, 0, stream>>>(cps, nullptr, S, gy, 0, pen116, nullptr);
    finalize_argmax<<<L, TPB, 0, stream>>>(sim116, S, pen116, idx116);
  }

  build_x16<<<cdiv(768 * 400, TPB), TPB, 0, stream>>>(t2, f116_0, f116_1, idx116, X16);
  conv1x1_v2<<<dim3(cdiv(400, 64), 256), TPB, 0, stream>>>(W16, X16, t2_, 256, 768, 400);

  // ---------------- conf18 (output) + idx18 (D=256, K2=1536) ----------------
  {
    int L = 1600, S = 1600, K2 = 1536;
    int gx = cdiv(S, 128), gy = cdiv(L, 128);
    pack_split2<<<dim3(cdiv(L * K2, TPB), 2), TPB, 0, stream>>>(f18_0, f18_1, pA, pB, L, 256, K2, CA, CB);
    gemm_bf16_nt<false, true><<<gx * gy, TPB, 0, stream>>>(pA, pB, conf18, L, S, K2, gx, gy,
                                                           cps, rps);
    logsum_combine2<<<dim3(cdiv(S, TPB), 2), TPB, 0, stream>>>(cps, rps, S, gy, gx, cls18, rls18);
    finalize_write<<<L, TPB, 0, stream>>>(conf18, S, cls18, rls18, idx18);
  }

  build_x8<<<cdiv(512 * 1600, TPB), TPB, 0, stream>>>(f18_0, f18_1, idx18, X8);
  conv1x1_v2<<<dim3(cdiv(1600, 64), 256), TPB, 0, stream>>>(W8, X8, conv18b, 256, 512, 1600);
  pool_k<<<cdiv(256 * 100, TPB), TPB, 0, stream>>>(conv18b, f18p, 256, 40, 4);
  pool_k<<<cdiv(256 * 100, TPB), TPB, 0, stream>>>(t2_, t2p, 256, 20, 2);

  // ---------------- conf14 -> idx14 (D=196, K2=1216; staged in conf12 region) ----
  {
    int L = 6400, S = 6400, K2 = 1216;
    int gx = cdiv(S, 256), gy = cdiv(L, 128);   // 25 x 50
    pack_split2<<<dim3(cdiv(L * K2, TPB), 2), TPB, 0, stream>>>(f14_0, f14_1, pA, pB, L, 196, K2, CA, CB);
    gemm_big<false><<<gx * gy, 512, 0, stream>>>(pA, pB, conf12, L, S, K2, gx, gy,
                                                 cps, nullptr);
    logsum_combine2<<<dim3(cdiv(S, TPB), 1), TPB, 0, stream>>>(cps, nullptr, S, gy, 0, pen14, nullptr);
    finalize_argmax<<<L, TPB, 0, stream>>>(conf12, S, pen14, idx14);
  }
  pool14<<<cdiv(392 * 100, TPB), TPB, 0, stream>>>(f14_0, f14_1, idx14, f14p);

  build_xt3<<<cdiv(1100 * 100, TPB), TPB, 0, stream>>>(t3, t2p, f18p, f14p, Xt3);
  conv1x1_v2<<<dim3(cdiv(100, 64), 128), TPB, 0, stream>>>(Wt3, Xt3, t3conv, 128, 1100, 100);
  pool_k<<<cdiv(128 * 25, TPB), TPB, 0, stream>>>(t3conv, t3d, 128, 10, 2);

  build_xt4<<<cdiv(256 * 25, TPB), TPB, 0, stream>>>(t3d, t4, Xt4);
  conv1x1_v2<<<dim3(cdiv(25, 64), 128), TPB, 0, stream>>>(Wt4, Xt4, t4d, 128, 256, 25);

  topic_k<<<cdiv(12800, TPB), TPB, 0, stream>>>(f12_0, f12_1, t4d, topic);

  // ---------------- conf12 (output, D=128, K2=768) ----------------
  {
    int L = 6400, S = 6400, K2 = 768;
    int gx = cdiv(S, 256), gy = cdiv(L, 128);   // 25 x 50
    pack_split2<<<dim3(cdiv(L * K2, TPB), 2), TPB, 0, stream>>>(f12_0, f12_1, pA, pB, L, 128, K2, CA, CB);
    gemm_big<true><<<gx * gy, 512, 0, stream>>>(pA, pB, conf12, L, S, K2, gx, gy,
                                                cps, rps);
    logsum_combine2<<<dim3(cdiv(S, TPB), 2), TPB, 0, stream>>>(cps, rps, S, gy, gx, cls12, rls12);
    finalize_mask<<<L, TPB, 0, stream>>>(conf12, S, cls12, rls12);
  }
}